// Round 5
// baseline (1378.383 us; speedup 1.0000x reference)
//
#include <hip/hip_runtime.h>
#include <math.h>

#define D_NODE 12
#define HS     16     // padded row stride for hidden buffers
#define BSH    7      // bucket shift: 128 nodes per bucket
#define BSZ    128
#define CHUNK  4096   // edges per partition block (P1/P2)
#define MAXNB  1024   // max buckets supported (nn <= 131072)

// ---------------- P1: per-(block,bucket) histogram of dst
__global__ __launch_bounds__(1024) void k_p1(
    const int* __restrict__ ei, long long ne, int NB, int* __restrict__ M)
{
    __shared__ int cnt[MAXNB];
    int t = threadIdx.x;
    for (int k = t; k < NB; k += 1024) cnt[k] = 0;
    __syncthreads();
    long long beg = (long long)blockIdx.x * CHUNK;
    long long end = beg + CHUNK; if (end > ne) end = ne;
    for (long long e = beg + t; e < end; e += 1024)
        atomicAdd(&cnt[ei[ne + e] >> BSH], 1);
    __syncthreads();
    int* row = M + (long long)blockIdx.x * NB;
    for (int k = t; k < NB; k += 1024) row[k] = cnt[k];
}

// ---------------- per-bucket column scan over blocks: M[b][k] -> exclusive prefix; tot[k] = column total
__global__ __launch_bounds__(256) void k_colscan(
    int* __restrict__ M, int nblk, int NB, int* __restrict__ tot)
{
    __shared__ int sums[256];
    int k = blockIdx.x;
    int t = threadIdx.x;
    int v[4]; int s = 0;                       // supports nblk <= 1024
#pragma unroll
    for (int j = 0; j < 4; ++j) {
        int b = t * 4 + j;
        v[j] = (b < nblk) ? M[(long long)b * NB + k] : 0;
        s += v[j];
    }
    sums[t] = s;
    __syncthreads();
    for (int d = 1; d < 256; d <<= 1) {
        int u = (t >= d) ? sums[t - d] : 0;
        __syncthreads();
        sums[t] += u;
        __syncthreads();
    }
    int base = (t == 0) ? 0 : sums[t - 1];
#pragma unroll
    for (int j = 0; j < 4; ++j) {
        int b = t * 4 + j;
        if (b < nblk) { M[(long long)b * NB + k] = base; base += v[j]; }
    }
    if (t == 255) tot[k] = sums[255];
}

// ---------------- tiny scan of bucket totals -> bucket bases bb[0..NB]
__global__ __launch_bounds__(1024) void k_bb(
    const int* __restrict__ tot, int NB, int* __restrict__ bb)
{
    __shared__ int part[1024];
    int t = threadIdx.x;
    part[t] = (t < NB) ? tot[t] : 0;
    __syncthreads();
    for (int d = 1; d < 1024; d <<= 1) {
        int v = (t >= d) ? part[t - d] : 0;
        __syncthreads();
        part[t] += v;
        __syncthreads();
    }
    if (t < NB) bb[t] = (t == 0) ? 0 : part[t - 1];
    if (t == NB - 1) bb[NB] = part[t];
}

// ---------------- P2: scatter edges into bucket-grouped order (LDS-ranked, no global atomics)
__global__ __launch_bounds__(1024) void k_p2(
    const int* __restrict__ ei, long long ne, const float4* __restrict__ attr,
    const int* __restrict__ M, const int* __restrict__ bb, int NB,
    unsigned* __restrict__ sp, float4* __restrict__ sattr)
{
    __shared__ int cnt[MAXNB];
    int t = threadIdx.x;
    const int* row = M + (long long)blockIdx.x * NB;
    for (int k = t; k < NB; k += 1024) cnt[k] = bb[k] + row[k];
    __syncthreads();
    long long beg = (long long)blockIdx.x * CHUNK;
    long long end = beg + CHUNK; if (end > ne) end = ne;
    for (long long e = beg + t; e < end; e += 1024) {
        int s = ei[e];
        int d = ei[ne + e];
        float4 a = attr[e];
        int k = d >> BSH;
        int p = atomicAdd(&cnt[k], 1);
        sp[p] = (unsigned)s | ((unsigned)(d & (BSZ - 1)) << 20);
        sattr[p] = a;
    }
}

// ---------------- Layer 0: bucket-block edge aggregation (LDS) + fused node linear + ELU
__global__ __launch_bounds__(1024, 8) void k_layer0(
    const float* __restrict__ x, long long nn,
    const int* __restrict__ bb, const unsigned* __restrict__ sp, const float4* __restrict__ sattr,
    const float* __restrict__ Wec1, const float* __restrict__ bec1,
    const float* __restrict__ Wl, const float* __restrict__ bl,
    float* __restrict__ hout)
{
    __shared__ float acc[12 * BSZ];
    __shared__ float sW1[48], sb1[12], sWl[180], sbl[15];
    int t = threadIdx.x;
    if (t < 48)  sW1[t] = Wec1[t];
    if (t < 12)  sb1[t] = bec1[t];
    if (t < 180) sWl[t] = Wl[t];
    if (t < 15)  sbl[t] = bl[t];
    for (int i = t; i < 12 * BSZ; i += 1024) acc[i] = 0.f;
    __syncthreads();
    int k = blockIdx.x;
    int beg = bb[k], end = bb[k + 1];
    for (int e = beg + t; e < end; e += 1024) {
        unsigned pk = sp[e];
        int s = pk & 0xFFFFF;
        int ld = pk >> 20;
        float4 a = sattr[e];
        const float4* xs = reinterpret_cast<const float4*>(x + (long long)s * D_NODE);
        float4 x0 = xs[0], x1 = xs[1], x2 = xs[2];
        float xv[12] = {x0.x,x0.y,x0.z,x0.w, x1.x,x1.y,x1.z,x1.w, x2.x,x2.y,x2.z,x2.w};
#pragma unroll
        for (int i = 0; i < 12; ++i) {
            float ea = sb1[i] + sW1[i*4+0]*a.x + sW1[i*4+1]*a.y + sW1[i*4+2]*a.z + sW1[i*4+3]*a.w;
            atomicAdd(&acc[i * BSZ + ld], fmaxf(xv[i] + ea, 0.f));
        }
    }
    __syncthreads();
    long long n = (long long)k * BSZ + t;
    if (t < BSZ && n < nn) {
        float v[12];
#pragma unroll
        for (int j = 0; j < 12; ++j) v[j] = x[n * D_NODE + j] + acc[j * BSZ + t];
        float* o = hout + n * HS;
#pragma unroll
        for (int i = 0; i < 15; ++i) {
            float r = sbl[i];
#pragma unroll
            for (int j = 0; j < 12; ++j) r += v[j] * sWl[i * 12 + j];
            o[i] = r > 0.f ? r : expm1f(r);
        }
        o[15] = 0.f;
    }
}

// ---------------- Layers 1/2: folded edge transform, LDS aggregation, fused node linear + ELU (+pool)
template<bool POOL, bool STORE>
__global__ __launch_bounds__(1024, 8) void k_layerK(
    const float* __restrict__ h, long long nn,
    const int* __restrict__ bb, const unsigned* __restrict__ sp, const float4* __restrict__ sattr,
    const float* __restrict__ Wec1, const float* __restrict__ bec1,
    const float* __restrict__ Wec2, const float* __restrict__ bec2,
    const float* __restrict__ Wl, const float* __restrict__ bl,
    float* __restrict__ hout, const int* __restrict__ batch, float* __restrict__ pooled)
{
    __shared__ float acc[15 * BSZ];
    __shared__ float sW12[60], sb12[15], sWl[225], sbl[15];
    int t = threadIdx.x;
    if (t < 60) {                       // fold W12 = Wec2 @ Wec1  (15x4)
        int i = t >> 2, kk = t & 3;
        float a = 0.f;
#pragma unroll
        for (int j = 0; j < 12; ++j) a += Wec2[i*12+j] * Wec1[j*4+kk];
        sW12[t] = a;
    }
    if (t < 15) {                       // b12 = Wec2 @ bec1 + bec2
        float a = bec2[t];
#pragma unroll
        for (int j = 0; j < 12; ++j) a += Wec2[t*12+j] * bec1[j];
        sb12[t] = a;
    }
    if (t < 225) sWl[t] = Wl[t];
    if (t < 15)  sbl[t] = bl[t];
    for (int i = t; i < 15 * BSZ; i += 1024) acc[i] = 0.f;
    __syncthreads();
    int k = blockIdx.x;
    int beg = bb[k], end = bb[k + 1];
    for (int e = beg + t; e < end; e += 1024) {
        unsigned pk = sp[e];
        int s = pk & 0xFFFFF;
        int ld = pk >> 20;
        float4 a = sattr[e];
        const float4* hs = reinterpret_cast<const float4*>(h + (long long)s * HS);
        float4 h0 = hs[0], h1 = hs[1], h2 = hs[2], h3 = hs[3];
        float hv[15] = {h0.x,h0.y,h0.z,h0.w, h1.x,h1.y,h1.z,h1.w,
                        h2.x,h2.y,h2.z,h2.w, h3.x,h3.y,h3.z};
#pragma unroll
        for (int i = 0; i < 15; ++i) {
            float e2 = sb12[i] + sW12[i*4+0]*a.x + sW12[i*4+1]*a.y + sW12[i*4+2]*a.z + sW12[i*4+3]*a.w;
            atomicAdd(&acc[i * BSZ + ld], fmaxf(hv[i] + e2, 0.f));
        }
    }
    __syncthreads();
    long long n = (long long)k * BSZ + t;
    if (t < BSZ && n < nn) {
        float v[15];
#pragma unroll
        for (int j = 0; j < 15; ++j) v[j] = h[n * HS + j] + acc[j * BSZ + t];
        float* o = STORE ? (hout + n * HS) : nullptr;
        long long pb = POOL ? (long long)batch[n] * HS : 0;
#pragma unroll
        for (int i = 0; i < 15; ++i) {
            float r = sbl[i];
#pragma unroll
            for (int j = 0; j < 15; ++j) r += v[j] * sWl[i * 15 + j];
            float hv2 = r > 0.f ? r : expm1f(r);
            if (STORE) o[i] = hv2;
            if (POOL) atomicAdd(&pooled[pb + i], hv2);
        }
        if (STORE) o[15] = 0.f;
    }
}

// ---------------- Head
__global__ __launch_bounds__(256) void k_head(
    const float* __restrict__ pooled, long long ng,
    const float* __restrict__ Wo1, const float* __restrict__ bo1,
    const float* __restrict__ Wo2, const float* __restrict__ bo2,
    float* __restrict__ out)
{
    long long g = (long long)blockIdx.x * 256 + threadIdx.x;
    if (g >= ng) return;
    float p[15], m[15];
#pragma unroll
    for (int j = 0; j < 15; ++j) p[j] = pooled[g * HS + j];
#pragma unroll
    for (int i = 0; i < 15; ++i) {
        float acc = bo1[i];
#pragma unroll
        for (int j = 0; j < 15; ++j) acc += p[j] * Wo1[i * 15 + j];
        m[i] = acc;
    }
#pragma unroll
    for (int i = 0; i < 2; ++i) {
        float acc = bo2[i];
#pragma unroll
        for (int j = 0; j < 15; ++j) acc += m[j] * Wo2[i * 15 + j];
        out[g * 2 + i] = acc;
    }
}

extern "C" void kernel_launch(void* const* d_in, const int* in_sizes, int n_in,
                              void* d_out, int out_size, void* d_ws, size_t ws_size,
                              hipStream_t stream)
{
    const float* x    = (const float*)d_in[0];
    const int*   ei   = (const int*)d_in[1];
    const float* attr = (const float*)d_in[2];
    const int*   batch= (const int*)d_in[3];
    const float* Wec1 = (const float*)d_in[4];
    const float* bec1 = (const float*)d_in[5];
    const float* Wec2 = (const float*)d_in[6];
    const float* bec2 = (const float*)d_in[7];
    const float* Wl0  = (const float*)d_in[8];
    const float* bl0  = (const float*)d_in[9];
    const float* Wl1  = (const float*)d_in[10];
    const float* bl1  = (const float*)d_in[11];
    const float* Wl2  = (const float*)d_in[12];
    const float* bl2  = (const float*)d_in[13];
    const float* Wo1  = (const float*)d_in[14];
    const float* bo1  = (const float*)d_in[15];
    const float* Wo2  = (const float*)d_in[16];
    const float* bo2  = (const float*)d_in[17];

    const long long nn = in_sizes[0] / D_NODE;   // 100000
    const long long ne = in_sizes[1] / 2;        // 3200000
    const long long ng = out_size / 2;           // 1024

    const int NB   = (int)((nn + BSZ - 1) >> BSH);           // 782
    const int nblk = (int)((ne + CHUNK - 1) / CHUNK);        // 782

    // ---- workspace layout ----
    char* w = (char*)d_ws;
    float4*   sattr = (float4*)w;                 w += (size_t)ne * sizeof(float4);
    unsigned* sp    = (unsigned*)w;               w += (size_t)ne * sizeof(unsigned);
    int*      M     = (int*)w;                    w += (size_t)nblk * NB * sizeof(int);
    int*      tot   = (int*)w;                    w += (size_t)NB * sizeof(int);
    int*      bb    = (int*)w;                    w += ((size_t)NB + 1) * sizeof(int);
    w = (char*)(((uintptr_t)w + 15) & ~(uintptr_t)15);
    float*    hA    = (float*)w;                  w += (size_t)nn * HS * sizeof(float);
    float*    hB    = (float*)w;                  w += (size_t)nn * HS * sizeof(float);
    float*    pooled= (float*)w;
    float*    out   = (float*)d_out;

    // ---- bucket-grouping build (shared by all 3 layers) ----
    k_p1<<<nblk, 1024, 0, stream>>>(ei, ne, NB, M);
    k_colscan<<<NB, 256, 0, stream>>>(M, nblk, NB, tot);
    k_bb<<<1, 1024, 0, stream>>>(tot, NB, bb);
    k_p2<<<nblk, 1024, 0, stream>>>(ei, ne, (const float4*)attr, M, bb, NB, sp, sattr);

    // ---- layers (edge aggregation + node update fused per bucket) ----
    k_layer0<<<NB, 1024, 0, stream>>>(x, nn, bb, sp, sattr, Wec1, bec1, Wl0, bl0, hA);
    k_layerK<false, true><<<NB, 1024, 0, stream>>>(hA, nn, bb, sp, sattr,
        Wec1, bec1, Wec2, bec2, Wl1, bl1, hB, nullptr, nullptr);
    hipMemsetAsync(pooled, 0, (size_t)ng * HS * sizeof(float), stream);
    k_layerK<true, false><<<NB, 1024, 0, stream>>>(hB, nn, bb, sp, sattr,
        Wec1, bec1, Wec2, bec2, Wl2, bl2, nullptr, batch, pooled);

    // ---- head ----
    k_head<<<(int)((ng + 255) / 256), 256, 0, stream>>>(pooled, ng, Wo1, bo1, Wo2, bo2, out);
}

// Round 6
// 1170.459 us; speedup vs baseline: 1.1776x; 1.1776x over previous
//
#include <hip/hip_runtime.h>
#include <math.h>

#define D_NODE 12
#define HS     16     // padded row stride for hidden buffers
#define BSH    7      // bucket shift: 128 nodes per bucket
#define BSZ    128
#define CHUNK  4096   // edges per partition block (P1/P2)
#define MAXNB  1024   // max buckets supported (nn <= 131072)
#define LT     512    // layer-kernel block size
#define ILP    4      // edges in flight per thread

// ---------------- P1: per-(block,bucket) histogram of dst
__global__ __launch_bounds__(1024) void k_p1(
    const int* __restrict__ ei, long long ne, int NB, int* __restrict__ M)
{
    __shared__ int cnt[MAXNB];
    int t = threadIdx.x;
    for (int k = t; k < NB; k += 1024) cnt[k] = 0;
    __syncthreads();
    long long beg = (long long)blockIdx.x * CHUNK;
    long long end = beg + CHUNK; if (end > ne) end = ne;
    for (long long e = beg + t; e < end; e += 1024)
        atomicAdd(&cnt[ei[ne + e] >> BSH], 1);
    __syncthreads();
    int* row = M + (long long)blockIdx.x * NB;
    for (int k = t; k < NB; k += 1024) row[k] = cnt[k];
}

// ---------------- per-bucket column scan over blocks
__global__ __launch_bounds__(256) void k_colscan(
    int* __restrict__ M, int nblk, int NB, int* __restrict__ tot)
{
    __shared__ int sums[256];
    int k = blockIdx.x;
    int t = threadIdx.x;
    int v[4]; int s = 0;                       // supports nblk <= 1024
#pragma unroll
    for (int j = 0; j < 4; ++j) {
        int b = t * 4 + j;
        v[j] = (b < nblk) ? M[(long long)b * NB + k] : 0;
        s += v[j];
    }
    sums[t] = s;
    __syncthreads();
    for (int d = 1; d < 256; d <<= 1) {
        int u = (t >= d) ? sums[t - d] : 0;
        __syncthreads();
        sums[t] += u;
        __syncthreads();
    }
    int base = (t == 0) ? 0 : sums[t - 1];
#pragma unroll
    for (int j = 0; j < 4; ++j) {
        int b = t * 4 + j;
        if (b < nblk) { M[(long long)b * NB + k] = base; base += v[j]; }
    }
    if (t == 255) tot[k] = sums[255];
}

// ---------------- tiny scan of bucket totals -> bucket bases bb[0..NB]
__global__ __launch_bounds__(1024) void k_bb(
    const int* __restrict__ tot, int NB, int* __restrict__ bb)
{
    __shared__ int part[1024];
    int t = threadIdx.x;
    part[t] = (t < NB) ? tot[t] : 0;
    __syncthreads();
    for (int d = 1; d < 1024; d <<= 1) {
        int v = (t >= d) ? part[t - d] : 0;
        __syncthreads();
        part[t] += v;
        __syncthreads();
    }
    if (t < NB) bb[t] = (t == 0) ? 0 : part[t - 1];
    if (t == NB - 1) bb[NB] = part[t];
}

// ---------------- P2: scatter edges into bucket-grouped order (LDS-ranked)
__global__ __launch_bounds__(1024) void k_p2(
    const int* __restrict__ ei, long long ne, const float4* __restrict__ attr,
    const int* __restrict__ M, const int* __restrict__ bb, int NB,
    unsigned* __restrict__ sp, float4* __restrict__ sattr)
{
    __shared__ int cnt[MAXNB];
    int t = threadIdx.x;
    const int* row = M + (long long)blockIdx.x * NB;
    for (int k = t; k < NB; k += 1024) cnt[k] = bb[k] + row[k];
    __syncthreads();
    long long beg = (long long)blockIdx.x * CHUNK;
    long long end = beg + CHUNK; if (end > ne) end = ne;
    for (long long e = beg + t; e < end; e += 1024) {
        int s = ei[e];
        int d = ei[ne + e];
        float4 a = attr[e];
        int k = d >> BSH;
        int p = atomicAdd(&cnt[k], 1);
        sp[p] = (unsigned)s | ((unsigned)(d & (BSZ - 1)) << 20);
        sattr[p] = a;
    }
}

// ---------------- Layer 0: 4-way-ILP edge aggregation (LDS) + fused node linear + ELU
__global__ __launch_bounds__(LT) void k_layer0(
    const float* __restrict__ x, long long nn,
    const int* __restrict__ bb, const unsigned* __restrict__ sp, const float4* __restrict__ sattr,
    const float* __restrict__ Wec1, const float* __restrict__ bec1,
    const float* __restrict__ Wl, const float* __restrict__ bl,
    float* __restrict__ hout)
{
    __shared__ float acc[12 * BSZ];
    __shared__ float sW1[48], sb1[12], sWl[180], sbl[15];
    int t = threadIdx.x;
    if (t < 48)  sW1[t] = Wec1[t];
    if (t < 12)  sb1[t] = bec1[t];
    if (t < 180) sWl[t] = Wl[t];
    if (t < 15)  sbl[t] = bl[t];
    for (int i = t; i < 12 * BSZ; i += LT) acc[i] = 0.f;
    __syncthreads();
    int k = blockIdx.x;
    int beg = bb[k], end = bb[k + 1];
    for (int e0 = beg + t; e0 < end; e0 += LT * ILP) {
        unsigned pk[ILP]; float4 at[ILP]; bool val[ILP];
#pragma unroll
        for (int j = 0; j < ILP; ++j) {
            int e = e0 + j * LT;
            val[j] = e < end;
            pk[j] = val[j] ? sp[e] : 0u;
        }
#pragma unroll
        for (int j = 0; j < ILP; ++j) {
            int e = e0 + j * LT;
            at[j] = val[j] ? sattr[e] : make_float4(0.f, 0.f, 0.f, 0.f);
        }
        float4 xr[ILP][3];
#pragma unroll
        for (int j = 0; j < ILP; ++j) {
            const float4* xs = reinterpret_cast<const float4*>(x + (long long)(pk[j] & 0xFFFFF) * D_NODE);
            xr[j][0] = xs[0]; xr[j][1] = xs[1]; xr[j][2] = xs[2];
        }
#pragma unroll
        for (int j = 0; j < ILP; ++j) {
            if (!val[j]) continue;
            int ld = pk[j] >> 20;
            float4 a = at[j];
            float xv[12] = {xr[j][0].x,xr[j][0].y,xr[j][0].z,xr[j][0].w,
                            xr[j][1].x,xr[j][1].y,xr[j][1].z,xr[j][1].w,
                            xr[j][2].x,xr[j][2].y,xr[j][2].z,xr[j][2].w};
#pragma unroll
            for (int i = 0; i < 12; ++i) {
                float ea = sb1[i] + sW1[i*4+0]*a.x + sW1[i*4+1]*a.y + sW1[i*4+2]*a.z + sW1[i*4+3]*a.w;
                atomicAdd(&acc[i * BSZ + ld], fmaxf(xv[i] + ea, 0.f));
            }
        }
    }
    __syncthreads();
    long long n = (long long)k * BSZ + t;
    if (t < BSZ && n < nn) {
        float v[12];
#pragma unroll
        for (int j = 0; j < 12; ++j) v[j] = x[n * D_NODE + j] + acc[j * BSZ + t];
        float* o = hout + n * HS;
#pragma unroll
        for (int i = 0; i < 15; ++i) {
            float r = sbl[i];
#pragma unroll
            for (int j = 0; j < 12; ++j) r += v[j] * sWl[i * 12 + j];
            o[i] = r > 0.f ? r : expm1f(r);
        }
        o[15] = 0.f;
    }
}

// ---------------- Layers 1/2: folded edge transform, 4-way ILP, LDS aggregation, fused node update
template<bool POOL, bool STORE>
__global__ __launch_bounds__(LT) void k_layerK(
    const float* __restrict__ h, long long nn,
    const int* __restrict__ bb, const unsigned* __restrict__ sp, const float4* __restrict__ sattr,
    const float* __restrict__ Wec1, const float* __restrict__ bec1,
    const float* __restrict__ Wec2, const float* __restrict__ bec2,
    const float* __restrict__ Wl, const float* __restrict__ bl,
    float* __restrict__ hout, const int* __restrict__ batch, float* __restrict__ pooled)
{
    __shared__ float acc[15 * BSZ];
    __shared__ float sW12[60], sb12[15], sWl[225], sbl[15];
    int t = threadIdx.x;
    if (t < 60) {                       // fold W12 = Wec2 @ Wec1  (15x4)
        int i = t >> 2, kk = t & 3;
        float a = 0.f;
#pragma unroll
        for (int j = 0; j < 12; ++j) a += Wec2[i*12+j] * Wec1[j*4+kk];
        sW12[t] = a;
    }
    if (t < 15) {                       // b12 = Wec2 @ bec1 + bec2
        float a = bec2[t];
#pragma unroll
        for (int j = 0; j < 12; ++j) a += Wec2[t*12+j] * bec1[j];
        sb12[t] = a;
    }
    if (t < 225) sWl[t] = Wl[t];
    if (t < 15)  sbl[t] = bl[t];
    for (int i = t; i < 15 * BSZ; i += LT) acc[i] = 0.f;
    __syncthreads();
    int k = blockIdx.x;
    int beg = bb[k], end = bb[k + 1];
    for (int e0 = beg + t; e0 < end; e0 += LT * ILP) {
        unsigned pk[ILP]; float4 at[ILP]; bool val[ILP];
#pragma unroll
        for (int j = 0; j < ILP; ++j) {
            int e = e0 + j * LT;
            val[j] = e < end;
            pk[j] = val[j] ? sp[e] : 0u;
        }
#pragma unroll
        for (int j = 0; j < ILP; ++j) {
            int e = e0 + j * LT;
            at[j] = val[j] ? sattr[e] : make_float4(0.f, 0.f, 0.f, 0.f);
        }
        float4 hr[ILP][4];
#pragma unroll
        for (int j = 0; j < ILP; ++j) {
            const float4* hs = reinterpret_cast<const float4*>(h + (long long)(pk[j] & 0xFFFFF) * HS);
            hr[j][0] = hs[0]; hr[j][1] = hs[1]; hr[j][2] = hs[2]; hr[j][3] = hs[3];
        }
#pragma unroll
        for (int j = 0; j < ILP; ++j) {
            if (!val[j]) continue;
            int ld = pk[j] >> 20;
            float4 a = at[j];
            float hv[15] = {hr[j][0].x,hr[j][0].y,hr[j][0].z,hr[j][0].w,
                            hr[j][1].x,hr[j][1].y,hr[j][1].z,hr[j][1].w,
                            hr[j][2].x,hr[j][2].y,hr[j][2].z,hr[j][2].w,
                            hr[j][3].x,hr[j][3].y,hr[j][3].z};
#pragma unroll
            for (int i = 0; i < 15; ++i) {
                float e2 = sb12[i] + sW12[i*4+0]*a.x + sW12[i*4+1]*a.y + sW12[i*4+2]*a.z + sW12[i*4+3]*a.w;
                atomicAdd(&acc[i * BSZ + ld], fmaxf(hv[i] + e2, 0.f));
            }
        }
    }
    __syncthreads();
    long long n = (long long)k * BSZ + t;
    if (t < BSZ && n < nn) {
        float v[15];
#pragma unroll
        for (int j = 0; j < 15; ++j) v[j] = h[n * HS + j] + acc[j * BSZ + t];
        float* o = STORE ? (hout + n * HS) : nullptr;
        long long pb = POOL ? (long long)batch[n] * HS : 0;
#pragma unroll
        for (int i = 0; i < 15; ++i) {
            float r = sbl[i];
#pragma unroll
            for (int j = 0; j < 15; ++j) r += v[j] * sWl[i * 15 + j];
            float hv2 = r > 0.f ? r : expm1f(r);
            if (STORE) o[i] = hv2;
            if (POOL) atomicAdd(&pooled[pb + i], hv2);
        }
        if (STORE) o[15] = 0.f;
    }
}

// ---------------- Head
__global__ __launch_bounds__(256) void k_head(
    const float* __restrict__ pooled, long long ng,
    const float* __restrict__ Wo1, const float* __restrict__ bo1,
    const float* __restrict__ Wo2, const float* __restrict__ bo2,
    float* __restrict__ out)
{
    long long g = (long long)blockIdx.x * 256 + threadIdx.x;
    if (g >= ng) return;
    float p[15], m[15];
#pragma unroll
    for (int j = 0; j < 15; ++j) p[j] = pooled[g * HS + j];
#pragma unroll
    for (int i = 0; i < 15; ++i) {
        float acc = bo1[i];
#pragma unroll
        for (int j = 0; j < 15; ++j) acc += p[j] * Wo1[i * 15 + j];
        m[i] = acc;
    }
#pragma unroll
    for (int i = 0; i < 2; ++i) {
        float acc = bo2[i];
#pragma unroll
        for (int j = 0; j < 15; ++j) acc += m[j] * Wo2[i * 15 + j];
        out[g * 2 + i] = acc;
    }
}

extern "C" void kernel_launch(void* const* d_in, const int* in_sizes, int n_in,
                              void* d_out, int out_size, void* d_ws, size_t ws_size,
                              hipStream_t stream)
{
    const float* x    = (const float*)d_in[0];
    const int*   ei   = (const int*)d_in[1];
    const float* attr = (const float*)d_in[2];
    const int*   batch= (const int*)d_in[3];
    const float* Wec1 = (const float*)d_in[4];
    const float* bec1 = (const float*)d_in[5];
    const float* Wec2 = (const float*)d_in[6];
    const float* bec2 = (const float*)d_in[7];
    const float* Wl0  = (const float*)d_in[8];
    const float* bl0  = (const float*)d_in[9];
    const float* Wl1  = (const float*)d_in[10];
    const float* bl1  = (const float*)d_in[11];
    const float* Wl2  = (const float*)d_in[12];
    const float* bl2  = (const float*)d_in[13];
    const float* Wo1  = (const float*)d_in[14];
    const float* bo1  = (const float*)d_in[15];
    const float* Wo2  = (const float*)d_in[16];
    const float* bo2  = (const float*)d_in[17];

    const long long nn = in_sizes[0] / D_NODE;   // 100000
    const long long ne = in_sizes[1] / 2;        // 3200000
    const long long ng = out_size / 2;           // 1024

    const int NB   = (int)((nn + BSZ - 1) >> BSH);           // 782
    const int nblk = (int)((ne + CHUNK - 1) / CHUNK);        // 782

    // ---- workspace layout ----
    char* w = (char*)d_ws;
    float4*   sattr = (float4*)w;                 w += (size_t)ne * sizeof(float4);
    unsigned* sp    = (unsigned*)w;               w += (size_t)ne * sizeof(unsigned);
    int*      M     = (int*)w;                    w += (size_t)nblk * NB * sizeof(int);
    int*      tot   = (int*)w;                    w += (size_t)NB * sizeof(int);
    int*      bb    = (int*)w;                    w += ((size_t)NB + 1) * sizeof(int);
    w = (char*)(((uintptr_t)w + 15) & ~(uintptr_t)15);
    float*    hA    = (float*)w;                  w += (size_t)nn * HS * sizeof(float);
    float*    hB    = (float*)w;                  w += (size_t)nn * HS * sizeof(float);
    float*    pooled= (float*)w;
    float*    out   = (float*)d_out;

    // ---- bucket-grouping build (shared by all 3 layers) ----
    k_p1<<<nblk, 1024, 0, stream>>>(ei, ne, NB, M);
    k_colscan<<<NB, 256, 0, stream>>>(M, nblk, NB, tot);
    k_bb<<<1, 1024, 0, stream>>>(tot, NB, bb);
    k_p2<<<nblk, 1024, 0, stream>>>(ei, ne, (const float4*)attr, M, bb, NB, sp, sattr);

    // ---- layers (edge aggregation + node update fused per bucket) ----
    k_layer0<<<NB, LT, 0, stream>>>(x, nn, bb, sp, sattr, Wec1, bec1, Wl0, bl0, hA);
    k_layerK<false, true><<<NB, LT, 0, stream>>>(hA, nn, bb, sp, sattr,
        Wec1, bec1, Wec2, bec2, Wl1, bl1, hB, nullptr, nullptr);
    hipMemsetAsync(pooled, 0, (size_t)ng * HS * sizeof(float), stream);
    k_layerK<true, false><<<NB, LT, 0, stream>>>(hB, nn, bb, sp, sattr,
        Wec1, bec1, Wec2, bec2, Wl2, bl2, nullptr, batch, pooled);

    // ---- head ----
    k_head<<<(int)((ng + 255) / 256), 256, 0, stream>>>(pooled, ng, Wo1, bo1, Wo2, bo2, out);
}

// Round 7
// 409.535 us; speedup vs baseline: 3.3657x; 2.8580x over previous
//
#include <hip/hip_runtime.h>
#include <math.h>

#define D_NODE 12
#define HS     16     // padded row stride for hidden buffers
#define BSH    7      // bucket shift: 128 nodes per bucket
#define BSZ    128
#define CHUNK  4096   // edges per partition block (P1/P2)
#define MAXNB  1024   // max buckets supported (nn <= 131072)

// ---------------- P1: per-(block,bucket) histogram of dst
__global__ __launch_bounds__(1024) void k_p1(
    const int* __restrict__ ei, long long ne, int NB, int* __restrict__ M)
{
    __shared__ int cnt[MAXNB];
    int t = threadIdx.x;
    for (int k = t; k < NB; k += 1024) cnt[k] = 0;
    __syncthreads();
    long long beg = (long long)blockIdx.x * CHUNK;
    long long end = beg + CHUNK; if (end > ne) end = ne;
    for (long long e = beg + t; e < end; e += 1024)
        atomicAdd(&cnt[ei[ne + e] >> BSH], 1);
    __syncthreads();
    int* row = M + (long long)blockIdx.x * NB;
    for (int k = t; k < NB; k += 1024) row[k] = cnt[k];
}

// ---------------- per-bucket column scan over blocks
__global__ __launch_bounds__(256) void k_colscan(
    int* __restrict__ M, int nblk, int NB, int* __restrict__ tot)
{
    __shared__ int sums[256];
    int k = blockIdx.x;
    int t = threadIdx.x;
    int v[4]; int s = 0;                       // supports nblk <= 1024
#pragma unroll
    for (int j = 0; j < 4; ++j) {
        int b = t * 4 + j;
        v[j] = (b < nblk) ? M[(long long)b * NB + k] : 0;
        s += v[j];
    }
    sums[t] = s;
    __syncthreads();
    for (int d = 1; d < 256; d <<= 1) {
        int u = (t >= d) ? sums[t - d] : 0;
        __syncthreads();
        sums[t] += u;
        __syncthreads();
    }
    int base = (t == 0) ? 0 : sums[t - 1];
#pragma unroll
    for (int j = 0; j < 4; ++j) {
        int b = t * 4 + j;
        if (b < nblk) { M[(long long)b * NB + k] = base; base += v[j]; }
    }
    if (t == 255) tot[k] = sums[255];
}

// ---------------- tiny scan of bucket totals -> bucket bases bb[0..NB]
__global__ __launch_bounds__(1024) void k_bb(
    const int* __restrict__ tot, int NB, int* __restrict__ bb)
{
    __shared__ int part[1024];
    int t = threadIdx.x;
    part[t] = (t < NB) ? tot[t] : 0;
    __syncthreads();
    for (int d = 1; d < 1024; d <<= 1) {
        int v = (t >= d) ? part[t - d] : 0;
        __syncthreads();
        part[t] += v;
        __syncthreads();
    }
    if (t < NB) bb[t] = (t == 0) ? 0 : part[t - 1];
    if (t == NB - 1) bb[NB] = part[t];
}

// ---------------- P2: scatter edges into bucket-grouped order (LDS-ranked)
__global__ __launch_bounds__(1024) void k_p2(
    const int* __restrict__ ei, long long ne, const float4* __restrict__ attr,
    const int* __restrict__ M, const int* __restrict__ bb, int NB,
    unsigned* __restrict__ sp1, float4* __restrict__ sattr1)
{
    __shared__ int cnt[MAXNB];
    int t = threadIdx.x;
    const int* row = M + (long long)blockIdx.x * NB;
    for (int k = t; k < NB; k += 1024) cnt[k] = bb[k] + row[k];
    __syncthreads();
    long long beg = (long long)blockIdx.x * CHUNK;
    long long end = beg + CHUNK; if (end > ne) end = ne;
    for (long long e = beg + t; e < end; e += 1024) {
        int s = ei[e];
        int d = ei[ne + e];
        float4 a = attr[e];
        int k = d >> BSH;
        int p = atomicAdd(&cnt[k], 1);
        sp1[p] = (unsigned)s | ((unsigned)(d & (BSZ - 1)) << 20);
        sattr1[p] = a;
    }
}

// ---------------- P3: within-bucket counting sort by local dst -> full dst-sorted CSR + off[]
__global__ __launch_bounds__(256) void k_p3(
    const unsigned* __restrict__ sp1, const float4* __restrict__ sattr1,
    const int* __restrict__ bb, int NB, long long nn,
    unsigned* __restrict__ sp2, float4* __restrict__ sattr2, int* __restrict__ off)
{
    __shared__ int cnt[BSZ];
    __shared__ int base[BSZ];
    int k = blockIdx.x, t = threadIdx.x;
    int beg = bb[k], end = bb[k + 1];
    if (t < BSZ) cnt[t] = 0;
    __syncthreads();
    for (int e = beg + t; e < end; e += 256)
        atomicAdd(&cnt[sp1[e] >> 20], 1);
    __syncthreads();
    if (t < BSZ) base[t] = cnt[t];
    __syncthreads();
    for (int d = 1; d < BSZ; d <<= 1) {        // inclusive scan
        int v = (t < BSZ && t >= d) ? base[t - d] : 0;
        __syncthreads();
        if (t < BSZ) base[t] += v;
        __syncthreads();
    }
    if (t < BSZ) {
        int excl = beg + base[t] - cnt[t];
        long long n = (long long)k * BSZ + t;
        if (n < nn) off[n] = excl;
        cnt[t] = excl;                          // scatter counters
    }
    if (k == NB - 1 && t == 0) off[nn] = end;
    __syncthreads();
    for (int e = beg + t; e < end; e += 256) {
        unsigned pk = sp1[e];
        int ld = pk >> 20;
        int p = atomicAdd(&cnt[ld], 1);
        sp2[p] = pk & 0xFFFFF;
        sattr2[p] = sattr1[e];
    }
}

// ---------------- Layer 0: 16 lanes per node, dim-per-lane CSR gather + fused linear + ELU
__global__ __launch_bounds__(256) void k_layer0(
    const float* __restrict__ x, long long nn, const int* __restrict__ off,
    const unsigned* __restrict__ sp2, const float4* __restrict__ sattr2,
    const float* __restrict__ Wec1, const float* __restrict__ bec1,
    const float* __restrict__ Wl, const float* __restrict__ bl,
    float* __restrict__ hout)
{
    __shared__ float sW1[64], sb1[16], sWl[256], sbl[16];
    int t = threadIdx.x;
    if (t < 64)  sW1[t] = (t < 48) ? Wec1[t] : 0.f;
    if (t < 16)  sb1[t] = (t < 12) ? bec1[t] : 0.f;
    { int i = t >> 4, j = t & 15;
      sWl[t] = (i < 15 && j < 12) ? Wl[i * 12 + j] : 0.f; }
    if (t < 16)  sbl[t] = (t < 15) ? bl[t] : 0.f;
    __syncthreads();
    int g = t >> 4, l = t & 15;
    long long n = (long long)blockIdx.x * 16 + g;
    if (n >= nn) return;
    int beg = off[n], end = off[n + 1];
    float w0 = sW1[l*4+0], w1 = sW1[l*4+1], w2 = sW1[l*4+2], w3 = sW1[l*4+3];
    float b1 = sb1[l];
    float xn = (l < 12) ? x[n * D_NODE + l] : 0.f;
    float acc = 0.f;
#pragma unroll 4
    for (int e = beg; e < end; ++e) {
        unsigned s = sp2[e];
        float4 a = sattr2[e];
        float xs = (l < 12) ? x[(long long)s * D_NODE + l] : 0.f;
        float ea = b1 + w0 * a.x + w1 * a.y + w2 * a.z + w3 * a.w;
        acc += fmaxf(xs + ea, 0.f);
    }
    float v = xn + acc;
    float r = sbl[l];
#pragma unroll
    for (int j = 0; j < 12; ++j) {
        float vj = __shfl(v, j, 16);
        r += vj * sWl[l * 16 + j];
    }
    float o = r > 0.f ? r : expm1f(r);
    hout[n * HS + l] = (l < 15) ? o : 0.f;
}

// ---------------- Layers 1/2: folded edge transform, 16 lanes/node, dim-per-lane
template<bool POOL, bool STORE>
__global__ __launch_bounds__(256) void k_layerK(
    const float* __restrict__ h, long long nn, const int* __restrict__ off,
    const unsigned* __restrict__ sp2, const float4* __restrict__ sattr2,
    const float* __restrict__ Wec1, const float* __restrict__ bec1,
    const float* __restrict__ Wec2, const float* __restrict__ bec2,
    const float* __restrict__ Wl, const float* __restrict__ bl,
    float* __restrict__ hout, const int* __restrict__ batch, float* __restrict__ pooled)
{
    __shared__ float sW12[64], sb12[16], sWl[256], sbl[16];
    int t = threadIdx.x;
    if (t < 64) {                        // fold W12 = Wec2 @ Wec1 (15x4, rows 15 zero)
        int i = t >> 2, kk = t & 3;
        float a = 0.f;
        if (i < 15) {
#pragma unroll
            for (int j = 0; j < 12; ++j) a += Wec2[i*12+j] * Wec1[j*4+kk];
        }
        sW12[t] = a;
    }
    if (t < 16) {                        // b12 = Wec2 @ bec1 + bec2
        float a = 0.f;
        if (t < 15) {
            a = bec2[t];
#pragma unroll
            for (int j = 0; j < 12; ++j) a += Wec2[t*12+j] * bec1[j];
        }
        sb12[t] = a;
    }
    { int i = t >> 4, j = t & 15;
      sWl[t] = (i < 15 && j < 15) ? Wl[i * 15 + j] : 0.f; }
    if (t < 16) sbl[t] = (t < 15) ? bl[t] : 0.f;
    __syncthreads();
    int g = t >> 4, l = t & 15;
    long long n = (long long)blockIdx.x * 16 + g;
    if (n >= nn) return;
    int beg = off[n], end = off[n + 1];
    float w0 = sW12[l*4+0], w1 = sW12[l*4+1], w2 = sW12[l*4+2], w3 = sW12[l*4+3];
    float b12 = sb12[l];
    float hn = h[n * HS + l];
    float acc = 0.f;
#pragma unroll 4
    for (int e = beg; e < end; ++e) {
        unsigned s = sp2[e];
        float4 a = sattr2[e];
        float hs = h[(long long)s * HS + l];
        float e2 = b12 + w0 * a.x + w1 * a.y + w2 * a.z + w3 * a.w;
        acc += fmaxf(hs + e2, 0.f);
    }
    float v = hn + acc;
    float r = sbl[l];
#pragma unroll
    for (int j = 0; j < 15; ++j) {
        float vj = __shfl(v, j, 16);
        r += vj * sWl[l * 16 + j];
    }
    float o = r > 0.f ? r : expm1f(r);
    if (STORE) hout[n * HS + l] = (l < 15) ? o : 0.f;
    if (POOL && l < 15) atomicAdd(&pooled[(long long)batch[n] * HS + l], o);
}

// ---------------- Head
__global__ __launch_bounds__(256) void k_head(
    const float* __restrict__ pooled, long long ng,
    const float* __restrict__ Wo1, const float* __restrict__ bo1,
    const float* __restrict__ Wo2, const float* __restrict__ bo2,
    float* __restrict__ out)
{
    long long g = (long long)blockIdx.x * 256 + threadIdx.x;
    if (g >= ng) return;
    float p[15], m[15];
#pragma unroll
    for (int j = 0; j < 15; ++j) p[j] = pooled[g * HS + j];
#pragma unroll
    for (int i = 0; i < 15; ++i) {
        float acc = bo1[i];
#pragma unroll
        for (int j = 0; j < 15; ++j) acc += p[j] * Wo1[i * 15 + j];
        m[i] = acc;
    }
#pragma unroll
    for (int i = 0; i < 2; ++i) {
        float acc = bo2[i];
#pragma unroll
        for (int j = 0; j < 15; ++j) acc += m[j] * Wo2[i * 15 + j];
        out[g * 2 + i] = acc;
    }
}

extern "C" void kernel_launch(void* const* d_in, const int* in_sizes, int n_in,
                              void* d_out, int out_size, void* d_ws, size_t ws_size,
                              hipStream_t stream)
{
    const float* x    = (const float*)d_in[0];
    const int*   ei   = (const int*)d_in[1];
    const float* attr = (const float*)d_in[2];
    const int*   batch= (const int*)d_in[3];
    const float* Wec1 = (const float*)d_in[4];
    const float* bec1 = (const float*)d_in[5];
    const float* Wec2 = (const float*)d_in[6];
    const float* bec2 = (const float*)d_in[7];
    const float* Wl0  = (const float*)d_in[8];
    const float* bl0  = (const float*)d_in[9];
    const float* Wl1  = (const float*)d_in[10];
    const float* bl1  = (const float*)d_in[11];
    const float* Wl2  = (const float*)d_in[12];
    const float* bl2  = (const float*)d_in[13];
    const float* Wo1  = (const float*)d_in[14];
    const float* bo1  = (const float*)d_in[15];
    const float* Wo2  = (const float*)d_in[16];
    const float* bo2  = (const float*)d_in[17];

    const long long nn = in_sizes[0] / D_NODE;   // 100000
    const long long ne = in_sizes[1] / 2;        // 3200000
    const long long ng = out_size / 2;           // 1024

    const int NB   = (int)((nn + BSZ - 1) >> BSH);           // 782
    const int nblk = (int)((ne + CHUNK - 1) / CHUNK);        // 782

    // ---- workspace layout ----
    char* w = (char*)d_ws;
    float4*   sattr1 = (float4*)w;                w += (size_t)ne * sizeof(float4);
    unsigned* sp1    = (unsigned*)w;              w += (size_t)ne * sizeof(unsigned);
    float4*   sattr2 = (float4*)w;                w += (size_t)ne * sizeof(float4);
    unsigned* sp2    = (unsigned*)w;              w += (size_t)ne * sizeof(unsigned);
    int*      M      = (int*)w;                   w += (size_t)nblk * NB * sizeof(int);
    int*      tot    = (int*)w;                   w += (size_t)NB * sizeof(int);
    int*      bb     = (int*)w;                   w += ((size_t)NB + 1) * sizeof(int);
    int*      off    = (int*)w;                   w += ((size_t)nn + 1) * sizeof(int);
    // overlay: hA/hB/pooled reuse the bucket-grouped region (dead after k_p3)
    float*    hA     = (float*)sattr1;
    float*    hB     = hA + (size_t)nn * HS;
    float*    pooled = hB + (size_t)nn * HS;
    float*    out    = (float*)d_out;

    // ---- build full dst-sorted CSR (shared by all 3 layers) ----
    k_p1<<<nblk, 1024, 0, stream>>>(ei, ne, NB, M);
    k_colscan<<<NB, 256, 0, stream>>>(M, nblk, NB, tot);
    k_bb<<<1, 1024, 0, stream>>>(tot, NB, bb);
    k_p2<<<nblk, 1024, 0, stream>>>(ei, ne, (const float4*)attr, M, bb, NB, sp1, sattr1);
    k_p3<<<NB, 256, 0, stream>>>(sp1, sattr1, bb, NB, nn, sp2, sattr2, off);

    // ---- layers (16 lanes per node, dim-per-lane) ----
    const int lblk = (int)((nn + 15) / 16);      // 6250
    k_layer0<<<lblk, 256, 0, stream>>>(x, nn, off, sp2, sattr2, Wec1, bec1, Wl0, bl0, hA);
    k_layerK<false, true><<<lblk, 256, 0, stream>>>(hA, nn, off, sp2, sattr2,
        Wec1, bec1, Wec2, bec2, Wl1, bl1, hB, nullptr, nullptr);
    hipMemsetAsync(pooled, 0, (size_t)ng * HS * sizeof(float), stream);
    k_layerK<true, false><<<lblk, 256, 0, stream>>>(hB, nn, off, sp2, sattr2,
        Wec1, bec1, Wec2, bec2, Wl2, bl2, nullptr, batch, pooled);

    // ---- head ----
    k_head<<<(int)((ng + 255) / 256), 256, 0, stream>>>(pooled, ng, Wo1, bo1, Wo2, bo2, out);
}

// Round 8
// 408.161 us; speedup vs baseline: 3.3771x; 1.0034x over previous
//
#include <hip/hip_runtime.h>
#include <math.h>

#define D_NODE 12
#define HS     16     // padded row stride for hidden buffers
#define BSH    7      // bucket shift: 128 nodes per bucket
#define BSZ    128
#define CHUNK  8192   // edges per partition block (P1/P2)
#define MAXNB  1024   // max buckets supported (nn <= 131072)

// ---------------- P1: per-(block,bucket) histogram of dst
__global__ __launch_bounds__(1024) void k_p1(
    const int* __restrict__ ei, long long ne, int NB, int* __restrict__ M)
{
    __shared__ int cnt[MAXNB];
    int t = threadIdx.x;
    for (int k = t; k < NB; k += 1024) cnt[k] = 0;
    __syncthreads();
    long long beg = (long long)blockIdx.x * CHUNK;
    long long end = beg + CHUNK; if (end > ne) end = ne;
    for (long long e = beg + t; e < end; e += 1024)
        atomicAdd(&cnt[ei[ne + e] >> BSH], 1);
    __syncthreads();
    int* row = M + (long long)blockIdx.x * NB;
    for (int k = t; k < NB; k += 1024) row[k] = cnt[k];
}

// ---------------- per-bucket column scan over blocks
__global__ __launch_bounds__(256) void k_colscan(
    int* __restrict__ M, int nblk, int NB, int* __restrict__ tot)
{
    __shared__ int sums[256];
    int k = blockIdx.x;
    int t = threadIdx.x;
    int v[4]; int s = 0;                       // supports nblk <= 1024
#pragma unroll
    for (int j = 0; j < 4; ++j) {
        int b = t * 4 + j;
        v[j] = (b < nblk) ? M[(long long)b * NB + k] : 0;
        s += v[j];
    }
    sums[t] = s;
    __syncthreads();
    for (int d = 1; d < 256; d <<= 1) {
        int u = (t >= d) ? sums[t - d] : 0;
        __syncthreads();
        sums[t] += u;
        __syncthreads();
    }
    int base = (t == 0) ? 0 : sums[t - 1];
#pragma unroll
    for (int j = 0; j < 4; ++j) {
        int b = t * 4 + j;
        if (b < nblk) { M[(long long)b * NB + k] = base; base += v[j]; }
    }
    if (t == 255) tot[k] = sums[255];
}

// ---------------- tiny scan of bucket totals -> bucket bases bb[0..NB]
__global__ __launch_bounds__(1024) void k_bb(
    const int* __restrict__ tot, int NB, int* __restrict__ bb)
{
    __shared__ int part[1024];
    int t = threadIdx.x;
    part[t] = (t < NB) ? tot[t] : 0;
    __syncthreads();
    for (int d = 1; d < 1024; d <<= 1) {
        int v = (t >= d) ? part[t - d] : 0;
        __syncthreads();
        part[t] += v;
        __syncthreads();
    }
    if (t < NB) bb[t] = (t == 0) ? 0 : part[t - 1];
    if (t == NB - 1) bb[NB] = part[t];
}

// ---------------- P2: bucket-group edges with COALESCED writes (LDS permutation staging)
__global__ __launch_bounds__(1024) void k_p2(
    const int* __restrict__ ei, long long ne, const float4* __restrict__ attr,
    const int* __restrict__ M, const int* __restrict__ bb, int NB,
    unsigned* __restrict__ sp1, float4* __restrict__ sattr1)
{
    __shared__ int lcnt[MAXNB];     // per-bucket counts (phase A), preserved
    __shared__ int lpos[MAXNB];     // inclusive scan of counts
    __shared__ int gb[MAXNB];       // global dest base per bucket for this block
    __shared__ int lperm[CHUNK];    // local output position -> edge id
    __shared__ int ldst[CHUNK];     // local output position -> global position
    int t = threadIdx.x;
    const int* row = M + (long long)blockIdx.x * NB;
    for (int k = t; k < MAXNB; k += 1024) {
        int c = (k < NB) ? (bb[k] + row[k]) : 0;
        gb[k] = c;
        lcnt[k] = 0;
    }
    __syncthreads();
    long long beg = (long long)blockIdx.x * CHUNK;
    long long end = beg + CHUNK; if (end > ne) end = ne;
    int nloc = (int)(end - beg);
    // ---- phase A: per-edge (bucket, rank)
    int k8[8], r8[8];
#pragma unroll
    for (int j = 0; j < 8; ++j) {
        long long e = beg + t + (long long)j * 1024;
        if (e < end) {
            int k = ei[ne + e] >> BSH;
            k8[j] = k;
            r8[j] = atomicAdd(&lcnt[k], 1);
        } else k8[j] = -1;
    }
    __syncthreads();
    // ---- phase B: block-local inclusive scan of lcnt -> lpos
    lpos[t] = lcnt[t];
    __syncthreads();
    for (int d = 1; d < MAXNB; d <<= 1) {
        int v = (t >= d) ? lpos[t - d] : 0;
        __syncthreads();
        lpos[t] += v;
        __syncthreads();
    }
    // ---- phase C: stage permutation
#pragma unroll
    for (int j = 0; j < 8; ++j) {
        if (k8[j] >= 0) {
            int k = k8[j], r = r8[j];
            int idx = lpos[k] - lcnt[k] + r;     // block-local exclusive base + rank
            long long e = beg + t + (long long)j * 1024;
            lperm[idx] = (int)e;
            ldst[idx] = gb[k] + r;
        }
    }
    __syncthreads();
    // ---- phase D: output-position-major, coalesced global writes
    for (int p = t; p < nloc; p += 1024) {
        int eid = lperm[p];
        int gd = ldst[p];
        int s = ei[eid];
        int d = ei[ne + eid];
        float4 a = attr[eid];
        sp1[gd] = (unsigned)s | ((unsigned)(d & (BSZ - 1)) << 20);
        sattr1[gd] = a;
    }
}

// ---------------- P3: within-bucket counting sort by local dst -> full dst-sorted CSR + off[]
__global__ __launch_bounds__(256) void k_p3(
    const unsigned* __restrict__ sp1, const float4* __restrict__ sattr1,
    const int* __restrict__ bb, int NB, long long nn,
    unsigned* __restrict__ sp2, float4* __restrict__ sattr2, int* __restrict__ off)
{
    __shared__ int cnt[BSZ];
    __shared__ int base[BSZ];
    int k = blockIdx.x, t = threadIdx.x;
    int beg = bb[k], end = bb[k + 1];
    if (t < BSZ) cnt[t] = 0;
    __syncthreads();
    for (int e = beg + t; e < end; e += 256)
        atomicAdd(&cnt[sp1[e] >> 20], 1);
    __syncthreads();
    if (t < BSZ) base[t] = cnt[t];
    __syncthreads();
    for (int d = 1; d < BSZ; d <<= 1) {        // inclusive scan
        int v = (t < BSZ && t >= d) ? base[t - d] : 0;
        __syncthreads();
        if (t < BSZ) base[t] += v;
        __syncthreads();
    }
    if (t < BSZ) {
        int excl = beg + base[t] - cnt[t];
        long long n = (long long)k * BSZ + t;
        if (n < nn) off[n] = excl;
        cnt[t] = excl;                          // scatter counters
    }
    if (k == NB - 1 && t == 0) off[nn] = end;
    __syncthreads();
    for (int e = beg + t; e < end; e += 256) {
        unsigned pk = sp1[e];
        int ld = pk >> 20;
        int p = atomicAdd(&cnt[ld], 1);
        sp2[p] = pk & 0xFFFFF;
        sattr2[p] = sattr1[e];
    }
}

// ---------------- Layer 0: 16 lanes per node, dim-per-lane CSR gather + fused linear + ELU
__global__ __launch_bounds__(256) void k_layer0(
    const float* __restrict__ x, long long nn, const int* __restrict__ off,
    const unsigned* __restrict__ sp2, const float4* __restrict__ sattr2,
    const float* __restrict__ Wec1, const float* __restrict__ bec1,
    const float* __restrict__ Wl, const float* __restrict__ bl,
    float* __restrict__ hout)
{
    __shared__ float sW1[64], sb1[16], sWl[256], sbl[16];
    int t = threadIdx.x;
    if (t < 64)  sW1[t] = (t < 48) ? Wec1[t] : 0.f;
    if (t < 16)  sb1[t] = (t < 12) ? bec1[t] : 0.f;
    { int i = t >> 4, j = t & 15;
      sWl[t] = (i < 15 && j < 12) ? Wl[i * 12 + j] : 0.f; }
    if (t < 16)  sbl[t] = (t < 15) ? bl[t] : 0.f;
    __syncthreads();
    int g = t >> 4, l = t & 15;
    long long n = (long long)blockIdx.x * 16 + g;
    if (n >= nn) return;
    int beg = off[n], end = off[n + 1];
    float w0 = sW1[l*4+0], w1 = sW1[l*4+1], w2 = sW1[l*4+2], w3 = sW1[l*4+3];
    float b1 = sb1[l];
    float xn = (l < 12) ? x[n * D_NODE + l] : 0.f;
    float acc = 0.f;
#pragma unroll 4
    for (int e = beg; e < end; ++e) {
        unsigned s = sp2[e];
        float4 a = sattr2[e];
        float xs = (l < 12) ? x[(long long)s * D_NODE + l] : 0.f;
        float ea = b1 + w0 * a.x + w1 * a.y + w2 * a.z + w3 * a.w;
        acc += fmaxf(xs + ea, 0.f);
    }
    float v = xn + acc;
    float r = sbl[l];
#pragma unroll
    for (int j = 0; j < 12; ++j) {
        float vj = __shfl(v, j, 16);
        r += vj * sWl[l * 16 + j];
    }
    float o = r > 0.f ? r : expm1f(r);
    hout[n * HS + l] = (l < 15) ? o : 0.f;
}

// ---------------- Layers 1/2: folded edge transform, 16 lanes/node, dim-per-lane
template<bool POOL, bool STORE>
__global__ __launch_bounds__(256) void k_layerK(
    const float* __restrict__ h, long long nn, const int* __restrict__ off,
    const unsigned* __restrict__ sp2, const float4* __restrict__ sattr2,
    const float* __restrict__ Wec1, const float* __restrict__ bec1,
    const float* __restrict__ Wec2, const float* __restrict__ bec2,
    const float* __restrict__ Wl, const float* __restrict__ bl,
    float* __restrict__ hout, const int* __restrict__ batch, float* __restrict__ pooled)
{
    __shared__ float sW12[64], sb12[16], sWl[256], sbl[16];
    int t = threadIdx.x;
    if (t < 64) {                        // fold W12 = Wec2 @ Wec1 (15x4, rows 15 zero)
        int i = t >> 2, kk = t & 3;
        float a = 0.f;
        if (i < 15) {
#pragma unroll
            for (int j = 0; j < 12; ++j) a += Wec2[i*12+j] * Wec1[j*4+kk];
        }
        sW12[t] = a;
    }
    if (t < 16) {                        // b12 = Wec2 @ bec1 + bec2
        float a = 0.f;
        if (t < 15) {
            a = bec2[t];
#pragma unroll
            for (int j = 0; j < 12; ++j) a += Wec2[t*12+j] * bec1[j];
        }
        sb12[t] = a;
    }
    { int i = t >> 4, j = t & 15;
      sWl[t] = (i < 15 && j < 15) ? Wl[i * 15 + j] : 0.f; }
    if (t < 16) sbl[t] = (t < 15) ? bl[t] : 0.f;
    __syncthreads();
    int g = t >> 4, l = t & 15;
    long long n = (long long)blockIdx.x * 16 + g;
    if (n >= nn) return;
    int beg = off[n], end = off[n + 1];
    float w0 = sW12[l*4+0], w1 = sW12[l*4+1], w2 = sW12[l*4+2], w3 = sW12[l*4+3];
    float b12 = sb12[l];
    float hn = h[n * HS + l];
    float acc = 0.f;
#pragma unroll 4
    for (int e = beg; e < end; ++e) {
        unsigned s = sp2[e];
        float4 a = sattr2[e];
        float hs = h[(long long)s * HS + l];
        float e2 = b12 + w0 * a.x + w1 * a.y + w2 * a.z + w3 * a.w;
        acc += fmaxf(hs + e2, 0.f);
    }
    float v = hn + acc;
    float r = sbl[l];
#pragma unroll
    for (int j = 0; j < 15; ++j) {
        float vj = __shfl(v, j, 16);
        r += vj * sWl[l * 16 + j];
    }
    float o = r > 0.f ? r : expm1f(r);
    if (STORE) hout[n * HS + l] = (l < 15) ? o : 0.f;
    if (POOL && l < 15) atomicAdd(&pooled[(long long)batch[n] * HS + l], o);
}

// ---------------- Head
__global__ __launch_bounds__(256) void k_head(
    const float* __restrict__ pooled, long long ng,
    const float* __restrict__ Wo1, const float* __restrict__ bo1,
    const float* __restrict__ Wo2, const float* __restrict__ bo2,
    float* __restrict__ out)
{
    long long g = (long long)blockIdx.x * 256 + threadIdx.x;
    if (g >= ng) return;
    float p[15], m[15];
#pragma unroll
    for (int j = 0; j < 15; ++j) p[j] = pooled[g * HS + j];
#pragma unroll
    for (int i = 0; i < 15; ++i) {
        float acc = bo1[i];
#pragma unroll
        for (int j = 0; j < 15; ++j) acc += p[j] * Wo1[i * 15 + j];
        m[i] = acc;
    }
#pragma unroll
    for (int i = 0; i < 2; ++i) {
        float acc = bo2[i];
#pragma unroll
        for (int j = 0; j < 15; ++j) acc += m[j] * Wo2[i * 15 + j];
        out[g * 2 + i] = acc;
    }
}

extern "C" void kernel_launch(void* const* d_in, const int* in_sizes, int n_in,
                              void* d_out, int out_size, void* d_ws, size_t ws_size,
                              hipStream_t stream)
{
    const float* x    = (const float*)d_in[0];
    const int*   ei   = (const int*)d_in[1];
    const float* attr = (const float*)d_in[2];
    const int*   batch= (const int*)d_in[3];
    const float* Wec1 = (const float*)d_in[4];
    const float* bec1 = (const float*)d_in[5];
    const float* Wec2 = (const float*)d_in[6];
    const float* bec2 = (const float*)d_in[7];
    const float* Wl0  = (const float*)d_in[8];
    const float* bl0  = (const float*)d_in[9];
    const float* Wl1  = (const float*)d_in[10];
    const float* bl1  = (const float*)d_in[11];
    const float* Wl2  = (const float*)d_in[12];
    const float* bl2  = (const float*)d_in[13];
    const float* Wo1  = (const float*)d_in[14];
    const float* bo1  = (const float*)d_in[15];
    const float* Wo2  = (const float*)d_in[16];
    const float* bo2  = (const float*)d_in[17];

    const long long nn = in_sizes[0] / D_NODE;   // 100000
    const long long ne = in_sizes[1] / 2;        // 3200000
    const long long ng = out_size / 2;           // 1024

    const int NB   = (int)((nn + BSZ - 1) >> BSH);           // 782
    const int nblk = (int)((ne + CHUNK - 1) / CHUNK);        // 391

    // ---- workspace layout ----
    char* w = (char*)d_ws;
    float4*   sattr1 = (float4*)w;                w += (size_t)ne * sizeof(float4);
    unsigned* sp1    = (unsigned*)w;              w += (size_t)ne * sizeof(unsigned);
    float4*   sattr2 = (float4*)w;                w += (size_t)ne * sizeof(float4);
    unsigned* sp2    = (unsigned*)w;              w += (size_t)ne * sizeof(unsigned);
    int*      M      = (int*)w;                   w += (size_t)nblk * NB * sizeof(int);
    int*      tot    = (int*)w;                   w += (size_t)NB * sizeof(int);
    int*      bb     = (int*)w;                   w += ((size_t)NB + 1) * sizeof(int);
    int*      off    = (int*)w;                   w += ((size_t)nn + 1) * sizeof(int);
    // overlay: hA/hB/pooled reuse the bucket-grouped region (dead after k_p3)
    float*    hA     = (float*)sattr1;
    float*    hB     = hA + (size_t)nn * HS;
    float*    pooled = hB + (size_t)nn * HS;
    float*    out    = (float*)d_out;

    // ---- build full dst-sorted CSR (shared by all 3 layers) ----
    k_p1<<<nblk, 1024, 0, stream>>>(ei, ne, NB, M);
    k_colscan<<<NB, 256, 0, stream>>>(M, nblk, NB, tot);
    k_bb<<<1, 1024, 0, stream>>>(tot, NB, bb);
    k_p2<<<nblk, 1024, 0, stream>>>(ei, ne, (const float4*)attr, M, bb, NB, sp1, sattr1);
    k_p3<<<NB, 256, 0, stream>>>(sp1, sattr1, bb, NB, nn, sp2, sattr2, off);

    // ---- layers (16 lanes per node, dim-per-lane) ----
    const int lblk = (int)((nn + 15) / 16);      // 6250
    k_layer0<<<lblk, 256, 0, stream>>>(x, nn, off, sp2, sattr2, Wec1, bec1, Wl0, bl0, hA);
    k_layerK<false, true><<<lblk, 256, 0, stream>>>(hA, nn, off, sp2, sattr2,
        Wec1, bec1, Wec2, bec2, Wl1, bl1, hB, nullptr, nullptr);
    hipMemsetAsync(pooled, 0, (size_t)ng * HS * sizeof(float), stream);
    k_layerK<true, false><<<lblk, 256, 0, stream>>>(hB, nn, off, sp2, sattr2,
        Wec1, bec1, Wec2, bec2, Wl2, bl2, nullptr, batch, pooled);

    // ---- head ----
    k_head<<<(int)((ng + 255) / 256), 256, 0, stream>>>(pooled, ng, Wo1, bo1, Wo2, bo2, out);
}

// Round 9
// 389.644 us; speedup vs baseline: 3.5375x; 1.0475x over previous
//
#include <hip/hip_runtime.h>
#include <math.h>

#define D_NODE 12
#define HS     16     // padded row stride for hidden buffers
#define BSH    7      // bucket shift: 128 nodes per bucket
#define BSZ    128
#define CHUNK  8192   // edges per partition block (P1/P2)
#define MAXNB  1024   // max buckets supported (nn <= 131072)

__device__ __forceinline__ int wave_iscan(int v, int lane) {
#pragma unroll
    for (int d = 1; d < 64; d <<= 1) {
        int u = __shfl_up(v, d, 64);
        if (lane >= d) v += u;
    }
    return v;
}

// ---------------- P1: per-(block,bucket) histogram of dst
__global__ __launch_bounds__(1024) void k_p1(
    const int* __restrict__ ei, long long ne, int NB, int* __restrict__ M)
{
    __shared__ int cnt[MAXNB];
    int t = threadIdx.x;
    for (int k = t; k < NB; k += 1024) cnt[k] = 0;
    __syncthreads();
    long long beg = (long long)blockIdx.x * CHUNK;
    long long end = beg + CHUNK; if (end > ne) end = ne;
    for (long long e = beg + t; e < end; e += 1024)
        atomicAdd(&cnt[ei[ne + e] >> BSH], 1);
    __syncthreads();
    int* row = M + (long long)blockIdx.x * NB;
    for (int k = t; k < NB; k += 1024) row[k] = cnt[k];
}

// ---------------- per-bucket column scan over blocks (wave-shuffle scan)
__global__ __launch_bounds__(256) void k_colscan(
    int* __restrict__ M, int nblk, int NB, int* __restrict__ tot)
{
    __shared__ int wsum[4];
    int k = blockIdx.x;
    int t = threadIdx.x;
    int lane = t & 63, wv = t >> 6;
    int v[4]; int s = 0;                       // supports nblk <= 1024
#pragma unroll
    for (int j = 0; j < 4; ++j) {
        int b = t * 4 + j;
        v[j] = (b < nblk) ? M[(long long)b * NB + k] : 0;
        s += v[j];
    }
    int inc = wave_iscan(s, lane);
    if (lane == 63) wsum[wv] = inc;
    __syncthreads();
    int base = inc - s;
#pragma unroll
    for (int j = 0; j < 4; ++j) { if (j < wv) base += wsum[j]; }
#pragma unroll
    for (int j = 0; j < 4; ++j) {
        int b = t * 4 + j;
        if (b < nblk) { M[(long long)b * NB + k] = base; base += v[j]; }
    }
    if (t == 255) tot[k] = base;               // total after last entry
}

// ---------------- scan of bucket totals -> exclusive bases bb[0..NB] (wave-shuffle)
__global__ __launch_bounds__(1024) void k_bb(
    const int* __restrict__ tot, int NB, int* __restrict__ bb)
{
    __shared__ int wsum[16];
    int t = threadIdx.x;
    int lane = t & 63, wv = t >> 6;
    int c = (t < NB) ? tot[t] : 0;
    int inc = wave_iscan(c, lane);
    if (lane == 63) wsum[wv] = inc;
    __syncthreads();
    if (t < 16) {
        int s2 = wsum[t];
#pragma unroll
        for (int d = 1; d < 16; d <<= 1) {
            int u = __shfl_up(s2, d, 64);
            if (t >= d) s2 += u;
        }
        wsum[t] = s2;                           // inclusive wave sums
    }
    __syncthreads();
    int base = (wv == 0) ? 0 : wsum[wv - 1];
    int incl = base + inc;
    if (t < NB) bb[t] = incl - c;               // exclusive
    if (t == NB - 1) bb[NB] = incl;
}

// ---------------- P2: bucket-group edges, coalesced writes, packed LDS permutation
__global__ __launch_bounds__(1024) void k_p2(
    const int* __restrict__ ei, long long ne, const float4* __restrict__ attr,
    const int* __restrict__ M, const int* __restrict__ bb, int NB,
    unsigned* __restrict__ sp1, float4* __restrict__ sattr1)
{
    __shared__ int lcnt[MAXNB];       // per-bucket counts (preserved)
    __shared__ int lpos[MAXNB];       // inclusive scan of counts
    __shared__ int gb[MAXNB];         // global dest base per bucket for this block
    __shared__ unsigned lperm[CHUNK]; // local output position -> (local edge | bucket<<13)
    __shared__ int wsum[16];
    int t = threadIdx.x;
    int lane = t & 63, wv = t >> 6;
    const int* row = M + (long long)blockIdx.x * NB;
    {
        int c = (t < NB) ? (bb[t] + row[t]) : 0;
        gb[t] = c;
        lcnt[t] = 0;
    }
    __syncthreads();
    long long beg = (long long)blockIdx.x * CHUNK;
    long long end = beg + CHUNK; if (end > ne) end = ne;
    int nloc = (int)(end - beg);
    // ---- phase A: per-edge (bucket, rank)
    int k8[8], r8[8];
#pragma unroll
    for (int j = 0; j < 8; ++j) {
        int le = t + j * 1024;
        if (beg + le < end) {
            int k = ei[ne + beg + le] >> BSH;
            k8[j] = k;
            r8[j] = atomicAdd(&lcnt[k], 1);
        } else k8[j] = -1;
    }
    __syncthreads();
    // ---- phase B: wave-shuffle inclusive scan of lcnt -> lpos
    int c = lcnt[t];
    int inc = wave_iscan(c, lane);
    if (lane == 63) wsum[wv] = inc;
    __syncthreads();
    if (t < 16) {
        int s2 = wsum[t];
#pragma unroll
        for (int d = 1; d < 16; d <<= 1) {
            int u = __shfl_up(s2, d, 64);
            if (t >= d) s2 += u;
        }
        wsum[t] = s2;
    }
    __syncthreads();
    lpos[t] = inc + ((wv == 0) ? 0 : wsum[wv - 1]);
    __syncthreads();
    // ---- phase C: stage packed permutation
#pragma unroll
    for (int j = 0; j < 8; ++j) {
        if (k8[j] >= 0) {
            int k = k8[j];
            int idx = lpos[k] - lcnt[k] + r8[j];
            lperm[idx] = (unsigned)(t + j * 1024) | ((unsigned)k << 13);
        }
    }
    __syncthreads();
    // ---- phase D: output-position-major, coalesced global writes
    for (int p = t; p < nloc; p += 1024) {
        unsigned u = lperm[p];
        int le = (int)(u & 8191);
        int lk = (int)(u >> 13);
        long long eid = beg + le;
        int s = ei[eid];
        int d = ei[ne + eid];
        float4 a = attr[eid];
        int gd = gb[lk] + (p - (lpos[lk] - lcnt[lk]));
        sp1[gd] = (unsigned)s | ((unsigned)(d & (BSZ - 1)) << 20);
        sattr1[gd] = a;
    }
}

// ---------------- P3: within-bucket counting sort by local dst -> dst-sorted CSR + off[]
__global__ __launch_bounds__(512) void k_p3(
    const unsigned* __restrict__ sp1, const float4* __restrict__ sattr1,
    const int* __restrict__ bb, int NB, long long nn,
    unsigned* __restrict__ sp2, float4* __restrict__ sattr2, int* __restrict__ off)
{
    __shared__ int cnt[BSZ];
    __shared__ int stage[BSZ];
    __shared__ int wsum0;
    int k = blockIdx.x, t = threadIdx.x;
    int lane = t & 63, wv = t >> 6;
    int beg = bb[k], end = bb[k + 1];
    if (t < BSZ) cnt[t] = 0;
    __syncthreads();
    for (int e = beg + t; e < end; e += 512)
        atomicAdd(&cnt[sp1[e] >> 20], 1);
    __syncthreads();
    if (t < BSZ) {
        int c = cnt[t];
        int inc = wave_iscan(c, lane);
        stage[t] = inc;
        if (lane == 63 && wv == 0) wsum0 = inc;
    }
    __syncthreads();
    if (t < BSZ) {
        int c = cnt[t];
        int incl = stage[t] + ((wv == 1) ? wsum0 : 0);
        int excl = beg + incl - c;
        long long n = (long long)k * BSZ + t;
        if (n < nn) off[n] = excl;
        cnt[t] = excl;                          // becomes scatter counter
    }
    if (k == NB - 1 && t == 0) off[nn] = end;
    __syncthreads();
    for (int e = beg + t; e < end; e += 512) {
        unsigned pk = sp1[e];
        int ld = pk >> 20;
        int p = atomicAdd(&cnt[ld], 1);
        sp2[p] = pk & 0xFFFFF;
        sattr2[p] = sattr1[e];
    }
}

// ---------------- Layer 0: 16 lanes per node, dim-per-lane CSR gather + fused linear + ELU
__global__ __launch_bounds__(256) void k_layer0(
    const float* __restrict__ x, long long nn, const int* __restrict__ off,
    const unsigned* __restrict__ sp2, const float4* __restrict__ sattr2,
    const float* __restrict__ Wec1, const float* __restrict__ bec1,
    const float* __restrict__ Wl, const float* __restrict__ bl,
    float* __restrict__ hout)
{
    __shared__ float sW1[64], sb1[16], sWl[256], sbl[16];
    int t = threadIdx.x;
    if (t < 64)  sW1[t] = (t < 48) ? Wec1[t] : 0.f;
    if (t < 16)  sb1[t] = (t < 12) ? bec1[t] : 0.f;
    { int i = t >> 4, j = t & 15;
      sWl[t] = (i < 15 && j < 12) ? Wl[i * 12 + j] : 0.f; }
    if (t < 16)  sbl[t] = (t < 15) ? bl[t] : 0.f;
    __syncthreads();
    int g = t >> 4, l = t & 15;
    long long n = (long long)blockIdx.x * 16 + g;
    if (n >= nn) return;
    int beg = off[n], end = off[n + 1];
    float w0 = sW1[l*4+0], w1 = sW1[l*4+1], w2 = sW1[l*4+2], w3 = sW1[l*4+3];
    float b1 = sb1[l];
    float xn = (l < 12) ? x[n * D_NODE + l] : 0.f;
    float acc = 0.f;
#pragma unroll 8
    for (int e = beg; e < end; ++e) {
        unsigned s = sp2[e];
        float4 a = sattr2[e];
        float xs = (l < 12) ? x[(long long)s * D_NODE + l] : 0.f;
        float ea = b1 + w0 * a.x + w1 * a.y + w2 * a.z + w3 * a.w;
        acc += fmaxf(xs + ea, 0.f);
    }
    float v = xn + acc;
    float r = sbl[l];
#pragma unroll
    for (int j = 0; j < 12; ++j) {
        float vj = __shfl(v, j, 16);
        r += vj * sWl[l * 16 + j];
    }
    float o = r > 0.f ? r : expm1f(r);
    hout[n * HS + l] = (l < 15) ? o : 0.f;
}

// ---------------- Layers 1/2: folded edge transform, 16 lanes/node, dim-per-lane
template<bool POOL, bool STORE>
__global__ __launch_bounds__(256) void k_layerK(
    const float* __restrict__ h, long long nn, const int* __restrict__ off,
    const unsigned* __restrict__ sp2, const float4* __restrict__ sattr2,
    const float* __restrict__ Wec1, const float* __restrict__ bec1,
    const float* __restrict__ Wec2, const float* __restrict__ bec2,
    const float* __restrict__ Wl, const float* __restrict__ bl,
    float* __restrict__ hout, const int* __restrict__ batch, float* __restrict__ pooled)
{
    __shared__ float sW12[64], sb12[16], sWl[256], sbl[16];
    int t = threadIdx.x;
    if (t < 64) {                        // fold W12 = Wec2 @ Wec1 (15x4, row 15 zero)
        int i = t >> 2, kk = t & 3;
        float a = 0.f;
        if (i < 15) {
#pragma unroll
            for (int j = 0; j < 12; ++j) a += Wec2[i*12+j] * Wec1[j*4+kk];
        }
        sW12[t] = a;
    }
    if (t < 16) {                        // b12 = Wec2 @ bec1 + bec2
        float a = 0.f;
        if (t < 15) {
            a = bec2[t];
#pragma unroll
            for (int j = 0; j < 12; ++j) a += Wec2[t*12+j] * bec1[j];
        }
        sb12[t] = a;
    }
    { int i = t >> 4, j = t & 15;
      sWl[t] = (i < 15 && j < 15) ? Wl[i * 15 + j] : 0.f; }
    if (t < 16) sbl[t] = (t < 15) ? bl[t] : 0.f;
    __syncthreads();
    int g = t >> 4, l = t & 15;
    long long n = (long long)blockIdx.x * 16 + g;
    if (n >= nn) return;
    int beg = off[n], end = off[n + 1];
    float w0 = sW12[l*4+0], w1 = sW12[l*4+1], w2 = sW12[l*4+2], w3 = sW12[l*4+3];
    float b12 = sb12[l];
    float hn = h[n * HS + l];
    float acc = 0.f;
#pragma unroll 8
    for (int e = beg; e < end; ++e) {
        unsigned s = sp2[e];
        float4 a = sattr2[e];
        float hs = h[(long long)s * HS + l];
        float e2 = b12 + w0 * a.x + w1 * a.y + w2 * a.z + w3 * a.w;
        acc += fmaxf(hs + e2, 0.f);
    }
    float v = hn + acc;
    float r = sbl[l];
#pragma unroll
    for (int j = 0; j < 15; ++j) {
        float vj = __shfl(v, j, 16);
        r += vj * sWl[l * 16 + j];
    }
    float o = r > 0.f ? r : expm1f(r);
    if (STORE) hout[n * HS + l] = (l < 15) ? o : 0.f;
    if (POOL && l < 15) atomicAdd(&pooled[(long long)batch[n] * HS + l], o);
}

// ---------------- Head
__global__ __launch_bounds__(256) void k_head(
    const float* __restrict__ pooled, long long ng,
    const float* __restrict__ Wo1, const float* __restrict__ bo1,
    const float* __restrict__ Wo2, const float* __restrict__ bo2,
    float* __restrict__ out)
{
    long long g = (long long)blockIdx.x * 256 + threadIdx.x;
    if (g >= ng) return;
    float p[15], m[15];
#pragma unroll
    for (int j = 0; j < 15; ++j) p[j] = pooled[g * HS + j];
#pragma unroll
    for (int i = 0; i < 15; ++i) {
        float acc = bo1[i];
#pragma unroll
        for (int j = 0; j < 15; ++j) acc += p[j] * Wo1[i * 15 + j];
        m[i] = acc;
    }
#pragma unroll
    for (int i = 0; i < 2; ++i) {
        float acc = bo2[i];
#pragma unroll
        for (int j = 0; j < 15; ++j) acc += m[j] * Wo2[i * 15 + j];
        out[g * 2 + i] = acc;
    }
}

extern "C" void kernel_launch(void* const* d_in, const int* in_sizes, int n_in,
                              void* d_out, int out_size, void* d_ws, size_t ws_size,
                              hipStream_t stream)
{
    const float* x    = (const float*)d_in[0];
    const int*   ei   = (const int*)d_in[1];
    const float* attr = (const float*)d_in[2];
    const int*   batch= (const int*)d_in[3];
    const float* Wec1 = (const float*)d_in[4];
    const float* bec1 = (const float*)d_in[5];
    const float* Wec2 = (const float*)d_in[6];
    const float* bec2 = (const float*)d_in[7];
    const float* Wl0  = (const float*)d_in[8];
    const float* bl0  = (const float*)d_in[9];
    const float* Wl1  = (const float*)d_in[10];
    const float* bl1  = (const float*)d_in[11];
    const float* Wl2  = (const float*)d_in[12];
    const float* bl2  = (const float*)d_in[13];
    const float* Wo1  = (const float*)d_in[14];
    const float* bo1  = (const float*)d_in[15];
    const float* Wo2  = (const float*)d_in[16];
    const float* bo2  = (const float*)d_in[17];

    const long long nn = in_sizes[0] / D_NODE;   // 100000
    const long long ne = in_sizes[1] / 2;        // 3200000
    const long long ng = out_size / 2;           // 1024

    const int NB   = (int)((nn + BSZ - 1) >> BSH);           // 782
    const int nblk = (int)((ne + CHUNK - 1) / CHUNK);        // 391

    // ---- workspace layout ----
    char* w = (char*)d_ws;
    float4*   sattr1 = (float4*)w;                w += (size_t)ne * sizeof(float4);
    unsigned* sp1    = (unsigned*)w;              w += (size_t)ne * sizeof(unsigned);
    float4*   sattr2 = (float4*)w;                w += (size_t)ne * sizeof(float4);
    unsigned* sp2    = (unsigned*)w;              w += (size_t)ne * sizeof(unsigned);
    int*      M      = (int*)w;                   w += (size_t)nblk * NB * sizeof(int);
    int*      tot    = (int*)w;                   w += (size_t)NB * sizeof(int);
    int*      bb     = (int*)w;                   w += ((size_t)NB + 1) * sizeof(int);
    int*      off    = (int*)w;                   w += ((size_t)nn + 1) * sizeof(int);
    // overlay: hA/hB/pooled reuse the bucket-grouped region (dead after k_p3)
    float*    hA     = (float*)sattr1;
    float*    hB     = hA + (size_t)nn * HS;
    float*    pooled = hB + (size_t)nn * HS;
    float*    out    = (float*)d_out;

    // ---- build full dst-sorted CSR (shared by all 3 layers) ----
    k_p1<<<nblk, 1024, 0, stream>>>(ei, ne, NB, M);
    k_colscan<<<NB, 256, 0, stream>>>(M, nblk, NB, tot);
    k_bb<<<1, 1024, 0, stream>>>(tot, NB, bb);
    k_p2<<<nblk, 1024, 0, stream>>>(ei, ne, (const float4*)attr, M, bb, NB, sp1, sattr1);
    k_p3<<<NB, 512, 0, stream>>>(sp1, sattr1, bb, NB, nn, sp2, sattr2, off);

    // ---- layers (16 lanes per node, dim-per-lane) ----
    const int lblk = (int)((nn + 15) / 16);      // 6250
    k_layer0<<<lblk, 256, 0, stream>>>(x, nn, off, sp2, sattr2, Wec1, bec1, Wl0, bl0, hA);
    k_layerK<false, true><<<lblk, 256, 0, stream>>>(hA, nn, off, sp2, sattr2,
        Wec1, bec1, Wec2, bec2, Wl1, bl1, hB, nullptr, nullptr);
    hipMemsetAsync(pooled, 0, (size_t)ng * HS * sizeof(float), stream);
    k_layerK<true, false><<<lblk, 256, 0, stream>>>(hB, nn, off, sp2, sattr2,
        Wec1, bec1, Wec2, bec2, Wl2, bl2, nullptr, batch, pooled);

    // ---- head ----
    k_head<<<(int)((ng + 255) / 256), 256, 0, stream>>>(pooled, ng, Wo1, bo1, Wo2, bo2, out);
}

// Round 10
// 362.484 us; speedup vs baseline: 3.8026x; 1.0749x over previous
//
#include <hip/hip_runtime.h>
#include <math.h>

#define D_NODE 12
#define HS     16     // padded row stride for hidden buffers
#define BSH    7      // bucket shift: 128 nodes per bucket
#define BSZ    128
#define CHUNK  8192   // edges per partition block (P1/P2)
#define HALF   4096   // staging half-chunk (P2)
#define MAXNB  1024   // max buckets supported (nn <= 131072)

__device__ __forceinline__ int wave_iscan(int v, int lane) {
#pragma unroll
    for (int d = 1; d < 64; d <<= 1) {
        int u = __shfl_up(v, d, 64);
        if (lane >= d) v += u;
    }
    return v;
}

// ---------------- P1: per-(block,bucket) histogram of dst
__global__ __launch_bounds__(1024) void k_p1(
    const int* __restrict__ ei, long long ne, int NB, int* __restrict__ M)
{
    __shared__ int cnt[MAXNB];
    int t = threadIdx.x;
    for (int k = t; k < NB; k += 1024) cnt[k] = 0;
    __syncthreads();
    long long beg = (long long)blockIdx.x * CHUNK;
    long long end = beg + CHUNK; if (end > ne) end = ne;
    for (long long e = beg + t; e < end; e += 1024)
        atomicAdd(&cnt[ei[ne + e] >> BSH], 1);
    __syncthreads();
    int* row = M + (long long)blockIdx.x * NB;
    for (int k = t; k < NB; k += 1024) row[k] = cnt[k];
}

// ---------------- per-bucket column scan over blocks (wave-shuffle scan)
__global__ __launch_bounds__(256) void k_colscan(
    int* __restrict__ M, int nblk, int NB, int* __restrict__ tot)
{
    __shared__ int wsum[4];
    int k = blockIdx.x;
    int t = threadIdx.x;
    int lane = t & 63, wv = t >> 6;
    int v[4]; int s = 0;                       // supports nblk <= 1024
#pragma unroll
    for (int j = 0; j < 4; ++j) {
        int b = t * 4 + j;
        v[j] = (b < nblk) ? M[(long long)b * NB + k] : 0;
        s += v[j];
    }
    int inc = wave_iscan(s, lane);
    if (lane == 63) wsum[wv] = inc;
    __syncthreads();
    int base = inc - s;
#pragma unroll
    for (int j = 0; j < 4; ++j) { if (j < wv) base += wsum[j]; }
#pragma unroll
    for (int j = 0; j < 4; ++j) {
        int b = t * 4 + j;
        if (b < nblk) { M[(long long)b * NB + k] = base; base += v[j]; }
    }
    if (t == 255) tot[k] = base;               // total after last entry
}

// ---------------- scan of bucket totals -> exclusive bases bb[0..NB] (wave-shuffle)
__global__ __launch_bounds__(1024) void k_bb(
    const int* __restrict__ tot, int NB, int* __restrict__ bb)
{
    __shared__ int wsum[16];
    int t = threadIdx.x;
    int lane = t & 63, wv = t >> 6;
    int c = (t < NB) ? tot[t] : 0;
    int inc = wave_iscan(c, lane);
    if (lane == 63) wsum[wv] = inc;
    __syncthreads();
    if (t < 16) {
        int s2 = wsum[t];
#pragma unroll
        for (int d = 1; d < 16; d <<= 1) {
            int u = __shfl_up(s2, d, 64);
            if (t >= d) s2 += u;
        }
        wsum[t] = s2;                           // inclusive wave sums
    }
    __syncthreads();
    int base = (wv == 0) ? 0 : wsum[wv - 1];
    int incl = base + inc;
    if (t < NB) bb[t] = incl - c;               // exclusive
    if (t == NB - 1) bb[NB] = incl;
}

// ---------------- P2: bucket-group edges; payload held in regs, 2-pass LDS staging,
//                  read-once + coalesced-write-once (no re-gather)
__global__ __launch_bounds__(1024) void k_p2(
    const int* __restrict__ ei, long long ne, const float4* __restrict__ attr,
    const int* __restrict__ M, const int* __restrict__ bb, int NB,
    unsigned* __restrict__ sp1, float4* __restrict__ sattr1)
{
    __shared__ int lcnt[MAXNB];       // per-bucket counts
    __shared__ int excl[MAXNB];       // block-local exclusive base per bucket
    __shared__ int gb[MAXNB];         // global dest base per bucket for this block
    __shared__ int wsum[16];
    __shared__ unsigned sp_st[HALF];  // staged packed sp
    __shared__ float4  sat_st[HALF];  // staged attr
    __shared__ int     gd_st[HALF];   // staged global dest
    int t = threadIdx.x;
    int lane = t & 63, wv = t >> 6;
    const int* row = M + (long long)blockIdx.x * NB;
    gb[t]   = (t < NB) ? (bb[t] + row[t]) : 0;
    lcnt[t] = 0;
    __syncthreads();
    long long beg = (long long)blockIdx.x * CHUNK;
    long long end = beg + CHUNK; if (end > ne) end = ne;
    int nloc = (int)(end - beg);
    // ---- phase A: read edges once, keep payload in registers, rank via LDS atomics
    unsigned pk8[8]; float4 a8[8]; int k8[8], r8[8];
#pragma unroll
    for (int j = 0; j < 8; ++j) {
        long long e = beg + t + (long long)j * 1024;
        if (e < end) {
            int s = ei[e];
            int d = ei[ne + e];
            a8[j] = attr[e];
            int k = d >> BSH;
            k8[j] = k;
            pk8[j] = (unsigned)s | ((unsigned)(d & (BSZ - 1)) << 20);
            r8[j] = atomicAdd(&lcnt[k], 1);
        } else k8[j] = -1;
    }
    __syncthreads();
    // ---- phase B: wave-shuffle scan of lcnt -> excl
    int c = lcnt[t];
    int inc = wave_iscan(c, lane);
    if (lane == 63) wsum[wv] = inc;
    __syncthreads();
    if (t < 16) {
        int s2 = wsum[t];
#pragma unroll
        for (int d = 1; d < 16; d <<= 1) {
            int u = __shfl_up(s2, d, 64);
            if (t >= d) s2 += u;
        }
        wsum[t] = s2;
    }
    __syncthreads();
    excl[t] = inc - c + ((wv == 0) ? 0 : wsum[wv - 1]);
    __syncthreads();
    int idx8[8];
#pragma unroll
    for (int j = 0; j < 8; ++j)
        idx8[j] = (k8[j] >= 0) ? (excl[k8[j]] + r8[j]) : -1;
    // ---- phases C/D: two staging passes, coalesced global writes
#pragma unroll
    for (int q = 0; q < 2; ++q) {
        int lo = q * HALF;
#pragma unroll
        for (int j = 0; j < 8; ++j) {
            int idx = idx8[j] - lo;
            if (idx8[j] >= 0 && idx >= 0 && idx < HALF) {
                sp_st[idx]  = pk8[j];
                sat_st[idx] = a8[j];
                gd_st[idx]  = gb[k8[j]] + r8[j];
            }
        }
        __syncthreads();
        for (int p = t; p < HALF; p += 1024) {
            int gp = lo + p;
            if (gp < nloc) {
                int gd = gd_st[p];
                sp1[gd]    = sp_st[p];
                sattr1[gd] = sat_st[p];
            }
        }
        __syncthreads();
    }
}

// ---------------- P3: within-bucket counting sort by local dst -> dst-sorted CSR + off[]
__global__ __launch_bounds__(1024) void k_p3(
    const unsigned* __restrict__ sp1, const float4* __restrict__ sattr1,
    const int* __restrict__ bb, int NB, long long nn,
    unsigned* __restrict__ sp2, float4* __restrict__ sattr2, int* __restrict__ off)
{
    __shared__ int cnt[BSZ];
    __shared__ int stage[BSZ];
    __shared__ int wsum0;
    int k = blockIdx.x, t = threadIdx.x;
    int lane = t & 63, wv = t >> 6;
    int beg = bb[k], end = bb[k + 1];
    if (t < BSZ) cnt[t] = 0;
    __syncthreads();
    for (int e = beg + t; e < end; e += 1024)
        atomicAdd(&cnt[sp1[e] >> 20], 1);
    __syncthreads();
    if (t < BSZ) {
        int c = cnt[t];
        int inc = wave_iscan(c, lane);
        stage[t] = inc;
        if (lane == 63 && wv == 0) wsum0 = inc;
    }
    __syncthreads();
    if (t < BSZ) {
        int c = cnt[t];
        int incl = stage[t] + ((wv == 1) ? wsum0 : 0);
        int excl = beg + incl - c;
        long long n = (long long)k * BSZ + t;
        if (n < nn) off[n] = excl;
        cnt[t] = excl;                          // becomes scatter counter
    }
    if (k == NB - 1 && t == 0) off[nn] = end;
    __syncthreads();
    for (int e = beg + t; e < end; e += 1024) {
        unsigned pk = sp1[e];
        int ld = pk >> 20;
        int p = atomicAdd(&cnt[ld], 1);
        sp2[p] = pk & 0xFFFFF;
        sattr2[p] = sattr1[e];
    }
}

// ---------------- Layer 0: 16 lanes per node, dim-per-lane CSR gather + fused linear + ELU
__global__ __launch_bounds__(256) void k_layer0(
    const float* __restrict__ x, long long nn, const int* __restrict__ off,
    const unsigned* __restrict__ sp2, const float4* __restrict__ sattr2,
    const float* __restrict__ Wec1, const float* __restrict__ bec1,
    const float* __restrict__ Wl, const float* __restrict__ bl,
    float* __restrict__ hout)
{
    __shared__ float sW1[64], sb1[16], sWl[256], sbl[16];
    int t = threadIdx.x;
    if (t < 64)  sW1[t] = (t < 48) ? Wec1[t] : 0.f;
    if (t < 16)  sb1[t] = (t < 12) ? bec1[t] : 0.f;
    { int i = t >> 4, j = t & 15;
      sWl[t] = (i < 15 && j < 12) ? Wl[i * 12 + j] : 0.f; }
    if (t < 16)  sbl[t] = (t < 15) ? bl[t] : 0.f;
    __syncthreads();
    int g = t >> 4, l = t & 15;
    long long n = (long long)blockIdx.x * 16 + g;
    if (n >= nn) return;
    int beg = off[n], end = off[n + 1];
    float w0 = sW1[l*4+0], w1 = sW1[l*4+1], w2 = sW1[l*4+2], w3 = sW1[l*4+3];
    float b1 = sb1[l];
    float xn = (l < 12) ? x[n * D_NODE + l] : 0.f;
    float acc = 0.f;
#pragma unroll 8
    for (int e = beg; e < end; ++e) {
        unsigned s = sp2[e];
        float4 a = sattr2[e];
        float xs = (l < 12) ? x[(long long)s * D_NODE + l] : 0.f;
        float ea = b1 + w0 * a.x + w1 * a.y + w2 * a.z + w3 * a.w;
        acc += fmaxf(xs + ea, 0.f);
    }
    float v = xn + acc;
    float r = sbl[l];
#pragma unroll
    for (int j = 0; j < 12; ++j) {
        float vj = __shfl(v, j, 16);
        r += vj * sWl[l * 16 + j];
    }
    float o = r > 0.f ? r : expm1f(r);
    hout[n * HS + l] = (l < 15) ? o : 0.f;
}

// ---------------- Layers 1/2: folded edge transform, 16 lanes/node, dim-per-lane
template<bool POOL, bool STORE>
__global__ __launch_bounds__(256) void k_layerK(
    const float* __restrict__ h, long long nn, const int* __restrict__ off,
    const unsigned* __restrict__ sp2, const float4* __restrict__ sattr2,
    const float* __restrict__ Wec1, const float* __restrict__ bec1,
    const float* __restrict__ Wec2, const float* __restrict__ bec2,
    const float* __restrict__ Wl, const float* __restrict__ bl,
    float* __restrict__ hout, const int* __restrict__ batch, float* __restrict__ pooled)
{
    __shared__ float sW12[64], sb12[16], sWl[256], sbl[16];
    int t = threadIdx.x;
    if (t < 64) {                        // fold W12 = Wec2 @ Wec1 (15x4, row 15 zero)
        int i = t >> 2, kk = t & 3;
        float a = 0.f;
        if (i < 15) {
#pragma unroll
            for (int j = 0; j < 12; ++j) a += Wec2[i*12+j] * Wec1[j*4+kk];
        }
        sW12[t] = a;
    }
    if (t < 16) {                        // b12 = Wec2 @ bec1 + bec2
        float a = 0.f;
        if (t < 15) {
            a = bec2[t];
#pragma unroll
            for (int j = 0; j < 12; ++j) a += Wec2[t*12+j] * bec1[j];
        }
        sb12[t] = a;
    }
    { int i = t >> 4, j = t & 15;
      sWl[t] = (i < 15 && j < 15) ? Wl[i * 15 + j] : 0.f; }
    if (t < 16) sbl[t] = (t < 15) ? bl[t] : 0.f;
    __syncthreads();
    int g = t >> 4, l = t & 15;
    long long n = (long long)blockIdx.x * 16 + g;
    if (n >= nn) return;
    int beg = off[n], end = off[n + 1];
    float w0 = sW12[l*4+0], w1 = sW12[l*4+1], w2 = sW12[l*4+2], w3 = sW12[l*4+3];
    float b12 = sb12[l];
    float hn = h[n * HS + l];
    float acc = 0.f;
#pragma unroll 8
    for (int e = beg; e < end; ++e) {
        unsigned s = sp2[e];
        float4 a = sattr2[e];
        float hs = h[(long long)s * HS + l];
        float e2 = b12 + w0 * a.x + w1 * a.y + w2 * a.z + w3 * a.w;
        acc += fmaxf(hs + e2, 0.f);
    }
    float v = hn + acc;
    float r = sbl[l];
#pragma unroll
    for (int j = 0; j < 15; ++j) {
        float vj = __shfl(v, j, 16);
        r += vj * sWl[l * 16 + j];
    }
    float o = r > 0.f ? r : expm1f(r);
    if (STORE) hout[n * HS + l] = (l < 15) ? o : 0.f;
    if (POOL && l < 15) atomicAdd(&pooled[(long long)batch[n] * HS + l], o);
}

// ---------------- Head
__global__ __launch_bounds__(256) void k_head(
    const float* __restrict__ pooled, long long ng,
    const float* __restrict__ Wo1, const float* __restrict__ bo1,
    const float* __restrict__ Wo2, const float* __restrict__ bo2,
    float* __restrict__ out)
{
    long long g = (long long)blockIdx.x * 256 + threadIdx.x;
    if (g >= ng) return;
    float p[15], m[15];
#pragma unroll
    for (int j = 0; j < 15; ++j) p[j] = pooled[g * HS + j];
#pragma unroll
    for (int i = 0; i < 15; ++i) {
        float acc = bo1[i];
#pragma unroll
        for (int j = 0; j < 15; ++j) acc += p[j] * Wo1[i * 15 + j];
        m[i] = acc;
    }
#pragma unroll
    for (int i = 0; i < 2; ++i) {
        float acc = bo2[i];
#pragma unroll
        for (int j = 0; j < 15; ++j) acc += m[j] * Wo2[i * 15 + j];
        out[g * 2 + i] = acc;
    }
}

extern "C" void kernel_launch(void* const* d_in, const int* in_sizes, int n_in,
                              void* d_out, int out_size, void* d_ws, size_t ws_size,
                              hipStream_t stream)
{
    const float* x    = (const float*)d_in[0];
    const int*   ei   = (const int*)d_in[1];
    const float* attr = (const float*)d_in[2];
    const int*   batch= (const int*)d_in[3];
    const float* Wec1 = (const float*)d_in[4];
    const float* bec1 = (const float*)d_in[5];
    const float* Wec2 = (const float*)d_in[6];
    const float* bec2 = (const float*)d_in[7];
    const float* Wl0  = (const float*)d_in[8];
    const float* bl0  = (const float*)d_in[9];
    const float* Wl1  = (const float*)d_in[10];
    const float* bl1  = (const float*)d_in[11];
    const float* Wl2  = (const float*)d_in[12];
    const float* bl2  = (const float*)d_in[13];
    const float* Wo1  = (const float*)d_in[14];
    const float* bo1  = (const float*)d_in[15];
    const float* Wo2  = (const float*)d_in[16];
    const float* bo2  = (const float*)d_in[17];

    const long long nn = in_sizes[0] / D_NODE;   // 100000
    const long long ne = in_sizes[1] / 2;        // 3200000
    const long long ng = out_size / 2;           // 1024

    const int NB   = (int)((nn + BSZ - 1) >> BSH);           // 782
    const int nblk = (int)((ne + CHUNK - 1) / CHUNK);        // 391

    // ---- workspace layout ----
    char* w = (char*)d_ws;
    float4*   sattr1 = (float4*)w;                w += (size_t)ne * sizeof(float4);
    unsigned* sp1    = (unsigned*)w;              w += (size_t)ne * sizeof(unsigned);
    float4*   sattr2 = (float4*)w;                w += (size_t)ne * sizeof(float4);
    unsigned* sp2    = (unsigned*)w;              w += (size_t)ne * sizeof(unsigned);
    int*      M      = (int*)w;                   w += (size_t)nblk * NB * sizeof(int);
    int*      tot    = (int*)w;                   w += (size_t)NB * sizeof(int);
    int*      bb     = (int*)w;                   w += ((size_t)NB + 1) * sizeof(int);
    int*      off    = (int*)w;                   w += ((size_t)nn + 1) * sizeof(int);
    // overlay: hA/hB/pooled reuse the bucket-grouped region (dead after k_p3)
    float*    hA     = (float*)sattr1;
    float*    hB     = hA + (size_t)nn * HS;
    float*    pooled = hB + (size_t)nn * HS;
    float*    out    = (float*)d_out;

    // ---- build full dst-sorted CSR (shared by all 3 layers) ----
    k_p1<<<nblk, 1024, 0, stream>>>(ei, ne, NB, M);
    k_colscan<<<NB, 256, 0, stream>>>(M, nblk, NB, tot);
    k_bb<<<1, 1024, 0, stream>>>(tot, NB, bb);
    k_p2<<<nblk, 1024, 0, stream>>>(ei, ne, (const float4*)attr, M, bb, NB, sp1, sattr1);
    k_p3<<<NB, 1024, 0, stream>>>(sp1, sattr1, bb, NB, nn, sp2, sattr2, off);

    // ---- layers (16 lanes per node, dim-per-lane) ----
    const int lblk = (int)((nn + 15) / 16);      // 6250
    k_layer0<<<lblk, 256, 0, stream>>>(x, nn, off, sp2, sattr2, Wec1, bec1, Wl0, bl0, hA);
    k_layerK<false, true><<<lblk, 256, 0, stream>>>(hA, nn, off, sp2, sattr2,
        Wec1, bec1, Wec2, bec2, Wl1, bl1, hB, nullptr, nullptr);
    hipMemsetAsync(pooled, 0, (size_t)ng * HS * sizeof(float), stream);
    k_layerK<true, false><<<lblk, 256, 0, stream>>>(hB, nn, off, sp2, sattr2,
        Wec1, bec1, Wec2, bec2, Wl2, bl2, nullptr, batch, pooled);

    // ---- head ----
    k_head<<<(int)((ng + 255) / 256), 256, 0, stream>>>(pooled, ng, Wo1, bo1, Wo2, bo2, out);
}

// Round 11
// 264.013 us; speedup vs baseline: 5.2209x; 1.3730x over previous
//
#include <hip/hip_runtime.h>
#include <hip/hip_fp16.h>
#include <math.h>

#define D_NODE 12
#define HS     16     // padded row stride for hidden buffers (elements)
#define BSH    7      // bucket shift: 128 nodes per bucket
#define BSZ    128
#define CHUNK  8192   // edges per partition block (P1/P2)
#define HALF   4096   // staging half-chunk (P2)
#define MAXNB  1024   // max buckets supported (nn <= 131072)

__device__ __forceinline__ int wave_iscan(int v, int lane) {
#pragma unroll
    for (int d = 1; d < 64; d <<= 1) {
        int u = __shfl_up(v, d, 64);
        if (lane >= d) v += u;
    }
    return v;
}

__device__ __forceinline__ uint2 pack4(float4 a) {
    __half2 lo = __floats2half2_rn(a.x, a.y);
    __half2 hi = __floats2half2_rn(a.z, a.w);
    uint2 r;
    r.x = *reinterpret_cast<unsigned*>(&lo);
    r.y = *reinterpret_cast<unsigned*>(&hi);
    return r;
}

__device__ __forceinline__ float4 unpack4(uint2 u) {
    __half2 lo = *reinterpret_cast<__half2*>(&u.x);
    __half2 hi = *reinterpret_cast<__half2*>(&u.y);
    float2 f0 = __half22float2(lo), f1 = __half22float2(hi);
    return make_float4(f0.x, f0.y, f1.x, f1.y);
}

// ---------------- convert x to padded fp16 table [nn][16]
__global__ __launch_bounds__(256) void k_xcvt(
    const float* __restrict__ x, long long nn, __half* __restrict__ xp)
{
    long long idx = (long long)blockIdx.x * 256 + threadIdx.x;
    if (idx >= nn * HS) return;
    long long n = idx >> 4;
    int l = (int)(idx & 15);
    xp[idx] = __float2half_rn((l < D_NODE) ? x[n * D_NODE + l] : 0.f);
}

// ---------------- P1: per-(block,bucket) histogram of dst
__global__ __launch_bounds__(1024) void k_p1(
    const int* __restrict__ ei, long long ne, int NB, int* __restrict__ M)
{
    __shared__ int cnt[MAXNB];
    int t = threadIdx.x;
    for (int k = t; k < NB; k += 1024) cnt[k] = 0;
    __syncthreads();
    long long beg = (long long)blockIdx.x * CHUNK;
    long long end = beg + CHUNK; if (end > ne) end = ne;
    for (long long e = beg + t; e < end; e += 1024)
        atomicAdd(&cnt[ei[ne + e] >> BSH], 1);
    __syncthreads();
    int* row = M + (long long)blockIdx.x * NB;
    for (int k = t; k < NB; k += 1024) row[k] = cnt[k];
}

// ---------------- per-bucket column scan over blocks (wave-shuffle scan)
__global__ __launch_bounds__(256) void k_colscan(
    int* __restrict__ M, int nblk, int NB, int* __restrict__ tot)
{
    __shared__ int wsum[4];
    int k = blockIdx.x;
    int t = threadIdx.x;
    int lane = t & 63, wv = t >> 6;
    int v[4]; int s = 0;                       // supports nblk <= 1024
#pragma unroll
    for (int j = 0; j < 4; ++j) {
        int b = t * 4 + j;
        v[j] = (b < nblk) ? M[(long long)b * NB + k] : 0;
        s += v[j];
    }
    int inc = wave_iscan(s, lane);
    if (lane == 63) wsum[wv] = inc;
    __syncthreads();
    int base = inc - s;
#pragma unroll
    for (int j = 0; j < 4; ++j) { if (j < wv) base += wsum[j]; }
#pragma unroll
    for (int j = 0; j < 4; ++j) {
        int b = t * 4 + j;
        if (b < nblk) { M[(long long)b * NB + k] = base; base += v[j]; }
    }
    if (t == 255) tot[k] = base;               // total after last entry
}

// ---------------- scan of bucket totals -> exclusive bases bb[0..NB] (wave-shuffle)
__global__ __launch_bounds__(1024) void k_bb(
    const int* __restrict__ tot, int NB, int* __restrict__ bb)
{
    __shared__ int wsum[16];
    int t = threadIdx.x;
    int lane = t & 63, wv = t >> 6;
    int c = (t < NB) ? tot[t] : 0;
    int inc = wave_iscan(c, lane);
    if (lane == 63) wsum[wv] = inc;
    __syncthreads();
    if (t < 16) {
        int s2 = wsum[t];
#pragma unroll
        for (int d = 1; d < 16; d <<= 1) {
            int u = __shfl_up(s2, d, 64);
            if (t >= d) s2 += u;
        }
        wsum[t] = s2;                           // inclusive wave sums
    }
    __syncthreads();
    int base = (wv == 0) ? 0 : wsum[wv - 1];
    int incl = base + inc;
    if (t < NB) bb[t] = incl - c;               // exclusive
    if (t == NB - 1) bb[NB] = incl;
}

// ---------------- P2: bucket-group edges; payload in regs (attr packed f16),
//                  2-pass LDS staging, read-once + coalesced-write-once
__global__ __launch_bounds__(1024) void k_p2(
    const int* __restrict__ ei, long long ne, const float4* __restrict__ attr,
    const int* __restrict__ M, const int* __restrict__ bb, int NB,
    unsigned* __restrict__ sp1, uint2* __restrict__ sattr1)
{
    __shared__ int lcnt[MAXNB];       // per-bucket counts
    __shared__ int excl[MAXNB];       // block-local exclusive base per bucket
    __shared__ int gb[MAXNB];         // global dest base per bucket for this block
    __shared__ int wsum[16];
    __shared__ unsigned sp_st[HALF];  // staged packed sp
    __shared__ uint2   sat_st[HALF];  // staged packed attr
    __shared__ int     gd_st[HALF];   // staged global dest
    int t = threadIdx.x;
    int lane = t & 63, wv = t >> 6;
    const int* row = M + (long long)blockIdx.x * NB;
    gb[t]   = (t < NB) ? (bb[t] + row[t]) : 0;
    lcnt[t] = 0;
    __syncthreads();
    long long beg = (long long)blockIdx.x * CHUNK;
    long long end = beg + CHUNK; if (end > ne) end = ne;
    int nloc = (int)(end - beg);
    // ---- phase A: read edges once, payload in regs, rank via LDS atomics
    unsigned pk8[8]; uint2 a8[8]; int k8[8], r8[8];
#pragma unroll
    for (int j = 0; j < 8; ++j) {
        long long e = beg + t + (long long)j * 1024;
        if (e < end) {
            int s = ei[e];
            int d = ei[ne + e];
            a8[j] = pack4(attr[e]);
            int k = d >> BSH;
            k8[j] = k;
            pk8[j] = (unsigned)s | ((unsigned)(d & (BSZ - 1)) << 20);
            r8[j] = atomicAdd(&lcnt[k], 1);
        } else k8[j] = -1;
    }
    __syncthreads();
    // ---- phase B: wave-shuffle scan of lcnt -> excl
    int c = lcnt[t];
    int inc = wave_iscan(c, lane);
    if (lane == 63) wsum[wv] = inc;
    __syncthreads();
    if (t < 16) {
        int s2 = wsum[t];
#pragma unroll
        for (int d = 1; d < 16; d <<= 1) {
            int u = __shfl_up(s2, d, 64);
            if (t >= d) s2 += u;
        }
        wsum[t] = s2;
    }
    __syncthreads();
    excl[t] = inc - c + ((wv == 0) ? 0 : wsum[wv - 1]);
    __syncthreads();
    int idx8[8];
#pragma unroll
    for (int j = 0; j < 8; ++j)
        idx8[j] = (k8[j] >= 0) ? (excl[k8[j]] + r8[j]) : -1;
    // ---- phases C/D: two staging passes, coalesced global writes
#pragma unroll
    for (int q = 0; q < 2; ++q) {
        int lo = q * HALF;
#pragma unroll
        for (int j = 0; j < 8; ++j) {
            int idx = idx8[j] - lo;
            if (idx8[j] >= 0 && idx >= 0 && idx < HALF) {
                sp_st[idx]  = pk8[j];
                sat_st[idx] = a8[j];
                gd_st[idx]  = gb[k8[j]] + r8[j];
            }
        }
        __syncthreads();
        for (int p = t; p < HALF; p += 1024) {
            int gp = lo + p;
            if (gp < nloc) {
                int gd = gd_st[p];
                sp1[gd]    = sp_st[p];
                sattr1[gd] = sat_st[p];
            }
        }
        __syncthreads();
    }
}

// ---------------- P3: within-bucket counting sort by local dst -> dst-sorted CSR + off[]
__global__ __launch_bounds__(1024) void k_p3(
    const unsigned* __restrict__ sp1, const uint2* __restrict__ sattr1,
    const int* __restrict__ bb, int NB, long long nn,
    unsigned* __restrict__ sp2, uint2* __restrict__ sattr2, int* __restrict__ off)
{
    __shared__ int cnt[BSZ];
    __shared__ int stage[BSZ];
    __shared__ int wsum0;
    int k = blockIdx.x, t = threadIdx.x;
    int lane = t & 63, wv = t >> 6;
    int beg = bb[k], end = bb[k + 1];
    if (t < BSZ) cnt[t] = 0;
    __syncthreads();
    for (int e = beg + t; e < end; e += 1024)
        atomicAdd(&cnt[sp1[e] >> 20], 1);
    __syncthreads();
    if (t < BSZ) {
        int c = cnt[t];
        int inc = wave_iscan(c, lane);
        stage[t] = inc;
        if (lane == 63 && wv == 0) wsum0 = inc;
    }
    __syncthreads();
    if (t < BSZ) {
        int c = cnt[t];
        int incl = stage[t] + ((wv == 1) ? wsum0 : 0);
        int excl = beg + incl - c;
        long long n = (long long)k * BSZ + t;
        if (n < nn) off[n] = excl;
        cnt[t] = excl;                          // becomes scatter counter
    }
    if (k == NB - 1 && t == 0) off[nn] = end;
    __syncthreads();
    for (int e = beg + t; e < end; e += 1024) {
        unsigned pk = sp1[e];
        int ld = pk >> 20;
        int p = atomicAdd(&cnt[ld], 1);
        sp2[p] = pk & 0xFFFFF;
        sattr2[p] = sattr1[e];
    }
}

// ---------------- Layer 0: 16 lanes/node, dim-per-lane; fp16 x table, packed attr
__global__ __launch_bounds__(256) void k_layer0(
    const __half* __restrict__ xp, long long nn, const int* __restrict__ off,
    const unsigned* __restrict__ sp2, const uint2* __restrict__ sattr2,
    const float* __restrict__ Wec1, const float* __restrict__ bec1,
    const float* __restrict__ Wl, const float* __restrict__ bl,
    __half* __restrict__ hout)
{
    __shared__ float sW1[64], sb1[16], sWl[16 * 17], sbl[16];
    int t = threadIdx.x;
    if (t < 64)  sW1[t] = (t < 48) ? Wec1[t] : 0.f;
    if (t < 16)  sb1[t] = (t < 12) ? bec1[t] : 0.f;
    { int i = t >> 4, j = t & 15;
      sWl[i * 17 + j] = (i < 15 && j < 12) ? Wl[i * 12 + j] : 0.f; }
    if (t < 16)  sbl[t] = (t < 15) ? bl[t] : 0.f;
    __syncthreads();
    int g = t >> 4, l = t & 15;
    long long n = (long long)blockIdx.x * 16 + g;
    if (n >= nn) return;
    int beg = off[n], end = off[n + 1];
    float w0 = sW1[l*4+0], w1 = sW1[l*4+1], w2 = sW1[l*4+2], w3 = sW1[l*4+3];
    float b1 = sb1[l];
    float xn = __half2float(xp[(n << 4) + l]);
    float acc = 0.f;
#pragma unroll 8
    for (int e = beg; e < end; ++e) {
        unsigned s = sp2[e];
        float4 a = unpack4(sattr2[e]);
        float xs = __half2float(xp[((long long)s << 4) + l]);
        float ea = b1 + w0 * a.x + w1 * a.y + w2 * a.z + w3 * a.w;
        acc += fmaxf(xs + ea, 0.f);
    }
    float v = xn + acc;
    float r = sbl[l];
#pragma unroll
    for (int j = 0; j < 12; ++j) {
        float vj = __shfl(v, j, 16);
        r += vj * sWl[l * 17 + j];
    }
    float o = r > 0.f ? r : expm1f(r);
    hout[(n << 4) + l] = __float2half_rn((l < 15) ? o : 0.f);
}

// ---------------- Layers 1/2: folded edge transform, fp16 h, packed attr
template<bool POOL, bool STORE>
__global__ __launch_bounds__(256) void k_layerK(
    const __half* __restrict__ h, long long nn, const int* __restrict__ off,
    const unsigned* __restrict__ sp2, const uint2* __restrict__ sattr2,
    const float* __restrict__ Wec1, const float* __restrict__ bec1,
    const float* __restrict__ Wec2, const float* __restrict__ bec2,
    const float* __restrict__ Wl, const float* __restrict__ bl,
    __half* __restrict__ hout, const int* __restrict__ batch, float* __restrict__ pooled)
{
    __shared__ float sW12[64], sb12[16], sWl[16 * 17], sbl[16];
    int t = threadIdx.x;
    if (t < 64) {                        // fold W12 = Wec2 @ Wec1 (15x4, row 15 zero)
        int i = t >> 2, kk = t & 3;
        float a = 0.f;
        if (i < 15) {
#pragma unroll
            for (int j = 0; j < 12; ++j) a += Wec2[i*12+j] * Wec1[j*4+kk];
        }
        sW12[t] = a;
    }
    if (t < 16) {                        // b12 = Wec2 @ bec1 + bec2
        float a = 0.f;
        if (t < 15) {
            a = bec2[t];
#pragma unroll
            for (int j = 0; j < 12; ++j) a += Wec2[t*12+j] * bec1[j];
        }
        sb12[t] = a;
    }
    { int i = t >> 4, j = t & 15;
      sWl[i * 17 + j] = (i < 15 && j < 15) ? Wl[i * 15 + j] : 0.f; }
    if (t < 16) sbl[t] = (t < 15) ? bl[t] : 0.f;
    __syncthreads();
    int g = t >> 4, l = t & 15;
    long long n = (long long)blockIdx.x * 16 + g;
    if (n >= nn) return;
    int beg = off[n], end = off[n + 1];
    float w0 = sW12[l*4+0], w1 = sW12[l*4+1], w2 = sW12[l*4+2], w3 = sW12[l*4+3];
    float b12 = sb12[l];
    float hn = __half2float(h[(n << 4) + l]);
    float acc = 0.f;
#pragma unroll 8
    for (int e = beg; e < end; ++e) {
        unsigned s = sp2[e];
        float4 a = unpack4(sattr2[e]);
        float hs = __half2float(h[((long long)s << 4) + l]);
        float e2 = b12 + w0 * a.x + w1 * a.y + w2 * a.z + w3 * a.w;
        acc += fmaxf(hs + e2, 0.f);
    }
    float v = hn + acc;
    float r = sbl[l];
#pragma unroll
    for (int j = 0; j < 15; ++j) {
        float vj = __shfl(v, j, 16);
        r += vj * sWl[l * 17 + j];
    }
    float o = r > 0.f ? r : expm1f(r);
    if (STORE) hout[(n << 4) + l] = __float2half_rn((l < 15) ? o : 0.f);
    if (POOL && l < 15) atomicAdd(&pooled[(long long)batch[n] * HS + l], o);
}

// ---------------- Head
__global__ __launch_bounds__(256) void k_head(
    const float* __restrict__ pooled, long long ng,
    const float* __restrict__ Wo1, const float* __restrict__ bo1,
    const float* __restrict__ Wo2, const float* __restrict__ bo2,
    float* __restrict__ out)
{
    long long g = (long long)blockIdx.x * 256 + threadIdx.x;
    if (g >= ng) return;
    float p[15], m[15];
#pragma unroll
    for (int j = 0; j < 15; ++j) p[j] = pooled[g * HS + j];
#pragma unroll
    for (int i = 0; i < 15; ++i) {
        float acc = bo1[i];
#pragma unroll
        for (int j = 0; j < 15; ++j) acc += p[j] * Wo1[i * 15 + j];
        m[i] = acc;
    }
#pragma unroll
    for (int i = 0; i < 2; ++i) {
        float acc = bo2[i];
#pragma unroll
        for (int j = 0; j < 15; ++j) acc += m[j] * Wo2[i * 15 + j];
        out[g * 2 + i] = acc;
    }
}

extern "C" void kernel_launch(void* const* d_in, const int* in_sizes, int n_in,
                              void* d_out, int out_size, void* d_ws, size_t ws_size,
                              hipStream_t stream)
{
    const float* x    = (const float*)d_in[0];
    const int*   ei   = (const int*)d_in[1];
    const float* attr = (const float*)d_in[2];
    const int*   batch= (const int*)d_in[3];
    const float* Wec1 = (const float*)d_in[4];
    const float* bec1 = (const float*)d_in[5];
    const float* Wec2 = (const float*)d_in[6];
    const float* bec2 = (const float*)d_in[7];
    const float* Wl0  = (const float*)d_in[8];
    const float* bl0  = (const float*)d_in[9];
    const float* Wl1  = (const float*)d_in[10];
    const float* bl1  = (const float*)d_in[11];
    const float* Wl2  = (const float*)d_in[12];
    const float* bl2  = (const float*)d_in[13];
    const float* Wo1  = (const float*)d_in[14];
    const float* bo1  = (const float*)d_in[15];
    const float* Wo2  = (const float*)d_in[16];
    const float* bo2  = (const float*)d_in[17];

    const long long nn = in_sizes[0] / D_NODE;   // 100000
    const long long ne = in_sizes[1] / 2;        // 3200000
    const long long ng = out_size / 2;           // 1024

    const int NB   = (int)((nn + BSZ - 1) >> BSH);           // 782
    const int nblk = (int)((ne + CHUNK - 1) / CHUNK);        // 391

    // ---- workspace layout ----
    char* w = (char*)d_ws;
    uint2*    sattr1 = (uint2*)w;                 w += (size_t)ne * sizeof(uint2);
    unsigned* sp1    = (unsigned*)w;              w += (size_t)ne * sizeof(unsigned);
    uint2*    sattr2 = (uint2*)w;                 w += (size_t)ne * sizeof(uint2);
    unsigned* sp2    = (unsigned*)w;              w += (size_t)ne * sizeof(unsigned);
    int*      M      = (int*)w;                   w += (size_t)nblk * NB * sizeof(int);
    int*      tot    = (int*)w;                   w += (size_t)NB * sizeof(int);
    int*      bb     = (int*)w;                   w += ((size_t)NB + 1) * sizeof(int);
    int*      off    = (int*)w;                   w += ((size_t)nn + 1) * sizeof(int);
    w = (char*)(((uintptr_t)w + 15) & ~(uintptr_t)15);
    __half*   xp     = (__half*)w;                w += (size_t)nn * HS * sizeof(__half);
    // overlay: hA/hB/pooled reuse the sattr1 region (dead after k_p3)
    __half*   hA     = (__half*)sattr1;
    __half*   hB     = hA + (size_t)nn * HS;
    float*    pooled = (float*)(hB + (size_t)nn * HS);
    float*    out    = (float*)d_out;

    // ---- x -> fp16 padded table (independent of sort) ----
    k_xcvt<<<(int)((nn * HS + 255) / 256), 256, 0, stream>>>(x, nn, xp);

    // ---- build full dst-sorted CSR (shared by all 3 layers) ----
    k_p1<<<nblk, 1024, 0, stream>>>(ei, ne, NB, M);
    k_colscan<<<NB, 256, 0, stream>>>(M, nblk, NB, tot);
    k_bb<<<1, 1024, 0, stream>>>(tot, NB, bb);
    k_p2<<<nblk, 1024, 0, stream>>>(ei, ne, (const float4*)attr, M, bb, NB, sp1, sattr1);
    k_p3<<<NB, 1024, 0, stream>>>(sp1, sattr1, bb, NB, nn, sp2, sattr2, off);

    // ---- layers (16 lanes per node, dim-per-lane) ----
    const int lblk = (int)((nn + 15) / 16);      // 6250
    k_layer0<<<lblk, 256, 0, stream>>>(xp, nn, off, sp2, sattr2, Wec1, bec1, Wl0, bl0, hA);
    k_layerK<false, true><<<lblk, 256, 0, stream>>>(hA, nn, off, sp2, sattr2,
        Wec1, bec1, Wec2, bec2, Wl1, bl1, hB, nullptr, nullptr);
    hipMemsetAsync(pooled, 0, (size_t)ng * HS * sizeof(float), stream);
    k_layerK<true, false><<<lblk, 256, 0, stream>>>(hB, nn, off, sp2, sattr2,
        Wec1, bec1, Wec2, bec2, Wl2, bl2, nullptr, batch, pooled);

    // ---- head ----
    k_head<<<(int)((ng + 255) / 256), 256, 0, stream>>>(pooled, ng, Wo1, bo1, Wo2, bo2, out);
}